// Round 3
// baseline (1135.012 us; speedup 1.0000x reference)
//
#include <hip/hip_runtime.h>
#include <hip/hip_bf16.h>
#include <cstdint>
#include <cstddef>

#define BS 2
#define SLEN 4096
#define DIM 2048
#define INNER 1024
#define NEXP 16
#define CAP 512
#define TPE (BS*CAP)      // 1024 tokens per expert
#define NTOK (BS*SLEN)    // 8192

typedef __attribute__((ext_vector_type(4))) float f32x4;
typedef __attribute__((ext_vector_type(8))) short s16x8;

static __device__ __forceinline__ unsigned short f2bf(float f){
  unsigned u = __float_as_uint(f);
  u += 0x7FFFu + ((u >> 16) & 1u);   // RNE
  return (unsigned short)(u >> 16);
}
static __device__ __forceinline__ float sigmoidf_(float x){ return 1.0f/(1.0f+expf(-x)); }

// async global -> LDS, 16B per lane. lds arg must be wave-uniform chunk base;
// HW writes base + lane*16 (m97/m104 semantics).
static __device__ __forceinline__ void gload16(const unsigned short* g, short* l){
  __builtin_amdgcn_global_load_lds(
      (const __attribute__((address_space(1))) void*)g,
      (__attribute__((address_space(3))) void*)l, 16, 0, 0);
}

// ---------------- cast fp32 -> bf16 (vectorized) ----------------
__global__ __launch_bounds__(256) void cast_kernel(const float* __restrict__ in,
    unsigned short* __restrict__ out, long n){
  long i = ((long)blockIdx.x*256 + threadIdx.x)*8;
  if (i >= n) return;
  f32x4 a = *reinterpret_cast<const f32x4*>(in+i);
  f32x4 b = *reinterpret_cast<const f32x4*>(in+i+4);
  s16x8 o;
  o[0]=(short)f2bf(a[0]); o[1]=(short)f2bf(a[1]); o[2]=(short)f2bf(a[2]); o[3]=(short)f2bf(a[3]);
  o[4]=(short)f2bf(b[0]); o[5]=(short)f2bf(b[1]); o[6]=(short)f2bf(b[2]); o[7]=(short)f2bf(b[3]);
  *reinterpret_cast<s16x8*>(out+i) = o;
}

// ------------- transpose + cast: in (R x C) fp32 -> out (C x R) bf16 -------------
__global__ __launch_bounds__(256) void transpose_cast_kernel(const float* __restrict__ in,
    unsigned short* __restrict__ out, int R, int C){
  __shared__ float tile[32][33];
  const size_t mat = blockIdx.z;
  const float* src = in + mat*(size_t)R*C;
  unsigned short* dst = out + mat*(size_t)R*C;
  int c0 = blockIdx.x*32, r0 = blockIdx.y*32;
  int tx = threadIdx.x, ty = threadIdx.y;
  #pragma unroll
  for (int i=0;i<32;i+=8)
    tile[ty+i][tx] = src[(size_t)(r0+ty+i)*C + (c0+tx)];
  __syncthreads();
  #pragma unroll
  for (int i=0;i<32;i+=8)
    dst[(size_t)(c0+ty+i)*R + (r0+tx)] = f2bf(tile[tx][ty+i]);
}

// ---------------- timestep part of router logits: tpart[b][e] ----------------
__global__ __launch_bounds__(256) void tpart_kernel(const float* __restrict__ timestep,
    const float* __restrict__ gate_w, float* __restrict__ tpart){
  int b = blockIdx.x >> 4, e = blockIdx.x & 15;
  float acc = 0.f;
  for (int d = threadIdx.x; d < DIM; d += 256)
    acc += timestep[b*DIM + d] * gate_w[(size_t)d*NEXP + e];
  #pragma unroll
  for (int o=32;o>0;o>>=1) acc += __shfl_down(acc, o);
  __shared__ float red[4];
  int lane = threadIdx.x & 63, wid = threadIdx.x >> 6;
  if (lane==0) red[wid] = acc;
  __syncthreads();
  if (threadIdx.x==0) tpart[blockIdx.x] = red[0]+red[1]+red[2]+red[3];
}

// ---------------- router: scores[b][e][s] = sigmoid(logit), fp32 ----------------
__global__ __launch_bounds__(256) void router_kernel(const float* __restrict__ xu,
    const float* __restrict__ gate_w, const float* __restrict__ tpart,
    float* __restrict__ scores){
  const int tok = blockIdx.x;
  const int b = tok >> 12;            // SLEN = 4096
  const int s = tok & (SLEN-1);
  const float* xr = xu + (size_t)tok*DIM;
  const int d0 = threadIdx.x * 8;
  f32x4 x0 = *reinterpret_cast<const f32x4*>(xr + d0);
  f32x4 x1 = *reinterpret_cast<const f32x4*>(xr + d0 + 4);
  float p[NEXP];
  #pragma unroll
  for (int e=0;e<NEXP;e++) p[e]=0.f;
  #pragma unroll
  for (int j=0;j<8;j++){
    float xv = (j<4) ? x0[j] : x1[j-4];
    const float* gw = gate_w + (size_t)(DIM + d0 + j)*NEXP;
    f32x4 g0 = *reinterpret_cast<const f32x4*>(gw);
    f32x4 g1 = *reinterpret_cast<const f32x4*>(gw+4);
    f32x4 g2 = *reinterpret_cast<const f32x4*>(gw+8);
    f32x4 g3 = *reinterpret_cast<const f32x4*>(gw+12);
    #pragma unroll
    for (int e=0;e<4;e++){ p[e]+=xv*g0[e]; p[4+e]+=xv*g1[e]; p[8+e]+=xv*g2[e]; p[12+e]+=xv*g3[e]; }
  }
  #pragma unroll
  for (int e=0;e<NEXP;e++){
    float v = p[e];
    #pragma unroll
    for (int o=32;o>0;o>>=1) v += __shfl_down(v, o);
    p[e] = v;
  }
  __shared__ float red[4][NEXP];
  int lane = threadIdx.x & 63, wid = threadIdx.x >> 6;
  if (lane==0){
    #pragma unroll
    for (int e=0;e<NEXP;e++) red[wid][e] = p[e];
  }
  __syncthreads();
  if (threadIdx.x < NEXP){
    int e = threadIdx.x;
    float v = red[0][e]+red[1][e]+red[2][e]+red[3][e] + tpart[b*NEXP+e];
    scores[((size_t)(b*NEXP+e))*SLEN + s] = sigmoidf_(v);
  }
}

// ---------------- top-512 per (b,e) via bitonic sort in LDS ----------------
__global__ __launch_bounds__(1024) void topk_kernel(const float* __restrict__ scores,
    int* __restrict__ tok_idx, float* __restrict__ gate_raw, float* __restrict__ token_sums){
  __shared__ unsigned long long keys[SLEN];
  const int b = blockIdx.x >> 4, e = blockIdx.x & 15;
  const float* sc = scores + (size_t)blockIdx.x * SLEN;   // row (b*16+e)
  for (int i = threadIdx.x; i < SLEN; i += 1024){
    unsigned bits = __float_as_uint(sc[i]);               // sigmoid outputs > 0 -> monotone bits
    keys[i] = ((unsigned long long)bits << 32) | (unsigned)(SLEN-1-i);  // tie: lower i wins
  }
  __syncthreads();
  for (int k = 2; k <= SLEN; k <<= 1){
    for (int j = k >> 1; j > 0; j >>= 1){
      for (int i = threadIdx.x; i < SLEN; i += 1024){
        int ixj = i ^ j;
        if (ixj > i){
          bool up = ((i & k) == 0);
          unsigned long long a = keys[i], c = keys[ixj];
          if ((a > c) == up){ keys[i] = c; keys[ixj] = a; }
        }
      }
      __syncthreads();
    }
  }
  for (int c = threadIdx.x; c < CAP; c += 1024){
    unsigned long long kk = keys[SLEN-1-c];
    int s = (SLEN-1) - (int)(kk & 0xFFFFFFFFull);
    float g = __uint_as_float((unsigned)(kk >> 32));
    int slot = (e*BS + b)*CAP + c;                         // matches ref (E, bs, cap) flat order
    tok_idx[slot]  = s;
    gate_raw[slot] = g;
    atomicAdd(&token_sums[b*SLEN + s], g);
  }
}

// ---------------- GEMM1: X(bf16) @ W[:, :2I] -> fused SwiGLU -> act bf16 ----------------
// BM=128, BN=64 act-cols (dual halves), BK=32, linear LDS, DOUBLE-BUFFERED
// global_load_lds width-16 staging (T3 2-phase: stage t+1 before compute t).
template<bool GATHER, bool SILU_FIRST>
__global__ __launch_bounds__(256) void gemm1_kernel(
    const unsigned short* __restrict__ X,    // [NTOK][DIM] bf16
    const unsigned short* __restrict__ WT,   // [mats][2*INNER][DIM] bf16 (n-major, k-contig)
    const int* __restrict__ tok_idx,
    unsigned short* __restrict__ act)        // [mats*rows][INNER] bf16
{
  const int e  = blockIdx.z;
  const int n0 = blockIdx.x * 64;
  const int m0 = blockIdx.y * 128;
  const int tid = threadIdx.x;
  const int wid = tid >> 6, lane = tid & 63;
  constexpr int NT = DIM/32;   // 64 K-tiles

  __shared__ short At[2][128*32];   // linear: row*32 + k, 64B rows
  __shared__ short Bg[2][64*32];
  __shared__ short Bu[2][64*32];

  // staging geometry: 1KB chunk per gload16 per wave; lane l -> row l/4, col (l%4)*8 shorts
  const int srow = lane >> 2;
  const int scol = (lane & 3) * 8;

  int ar0 = wid*32 + srow;       // A rows for this wave's two chunks
  int ar1 = ar0 + 16;
  size_t ab0, ab1;
  if (GATHER) {
    int s0 = m0 + ar0, s1 = m0 + ar1;
    int b0 = s0 >> 9, b1 = s1 >> 9;
    int t0 = tok_idx[(e*BS + b0)*CAP + (s0 & (CAP-1))];
    int t1 = tok_idx[(e*BS + b1)*CAP + (s1 & (CAP-1))];
    ab0 = ((size_t)(b0*SLEN + t0))*DIM + scol;
    ab1 = ((size_t)(b1*SLEN + t1))*DIM + scol;
  } else {
    ab0 = ((size_t)(m0 + ar0))*DIM + scol;
    ab1 = ((size_t)(m0 + ar1))*DIM + scol;
  }
  const unsigned short* a0 = X + ab0;
  const unsigned short* a1 = X + ab1;
  const unsigned short* WTe = WT + (size_t)e * (2*INNER) * (size_t)DIM;
  const int brow = wid*16 + srow;   // 0..63
  const unsigned short* bg = WTe + ((size_t)(n0 + brow))*DIM + scol;
  const unsigned short* bu = WTe + ((size_t)(INNER + n0 + brow))*DIM + scol;

  const int wr = wid >> 1, wc = wid & 1;
  const int lr = lane & 15, kg = (lane >> 4) * 8;

  f32x4 accg[4][2], accu[4][2];
  #pragma unroll
  for (int i=0;i<4;i++){
    #pragma unroll
    for (int j=0;j<2;j++){ accg[i][j] = (f32x4)0.0f; accu[i][j] = (f32x4)0.0f; }
  }

  auto stage = [&](int bsel, int t){
    int kb = t*32;
    gload16(a0 + kb, &At[bsel][(wid*2+0)*512]);
    gload16(a1 + kb, &At[bsel][(wid*2+1)*512]);
    gload16(bg + kb, &Bg[bsel][wid*512]);
    gload16(bu + kb, &Bu[bsel][wid*512]);
  };
  auto comp = [&](int bsel){
    s16x8 af[4], gf[2], uf[2];
    #pragma unroll
    for (int mi=0;mi<4;mi++) af[mi] = *reinterpret_cast<const s16x8*>(&At[bsel][(wr*64+mi*16+lr)*32 + kg]);
    #pragma unroll
    for (int ni=0;ni<2;ni++){
      gf[ni] = *reinterpret_cast<const s16x8*>(&Bg[bsel][(wc*32+ni*16+lr)*32 + kg]);
      uf[ni] = *reinterpret_cast<const s16x8*>(&Bu[bsel][(wc*32+ni*16+lr)*32 + kg]);
    }
    #pragma unroll
    for (int mi=0;mi<4;mi++){
      #pragma unroll
      for (int ni=0;ni<2;ni++){
        accg[mi][ni] = __builtin_amdgcn_mfma_f32_16x16x32_bf16(af[mi], gf[ni], accg[mi][ni], 0, 0, 0);
        accu[mi][ni] = __builtin_amdgcn_mfma_f32_16x16x32_bf16(af[mi], uf[ni], accu[mi][ni], 0, 0, 0);
      }
    }
  };

  stage(0, 0);
  __syncthreads();
  for (int t = 0; t + 2 <= NT - 1; t += 2){
    stage(1, t+1); comp(0); __syncthreads();
    stage(0, t+2); comp(1); __syncthreads();
  }
  stage(1, NT-1); comp(0); __syncthreads();
  comp(1);

  const size_t rowbase = GATHER ? (size_t)e * TPE : (size_t)0;
  #pragma unroll
  for (int mi=0;mi<4;mi++){
    #pragma unroll
    for (int ni=0;ni<2;ni++){
      #pragma unroll
      for (int r=0;r<4;r++){
        float g = accg[mi][ni][r], u = accu[mi][ni][r];
        float a = SILU_FIRST ? (g*sigmoidf_(g))*u : g*(u*sigmoidf_(u));
        int row = m0 + wr*64 + mi*16 + (lane>>4)*4 + r;
        int col = n0 + wc*32 + ni*16 + lr;
        act[(rowbase + row)*(size_t)INNER + col] = f2bf(a);
      }
    }
  }
}

// ---------------- GEMM2: act(bf16) @ W2 -> out fp32 (store or scaled atomicAdd) ----------------
// BM=128, BN=128, BK=32, linear LDS, double-buffered gload_lds staging; wave tile 64x64.
template<bool ROUTED>
__global__ __launch_bounds__(256) void gemm2_kernel(
    const unsigned short* __restrict__ act,  // [rows][INNER] bf16
    const unsigned short* __restrict__ W2T,  // [mats][DIM][INNER] bf16
    const int* __restrict__ tok_idx,
    const float* __restrict__ gate_raw,
    const float* __restrict__ token_sums,
    float* __restrict__ out)                 // [NTOK][DIM] fp32
{
  const int e  = blockIdx.z;
  const int n0 = blockIdx.x * 128;
  const int m0 = blockIdx.y * 128;
  const int tid = threadIdx.x;
  const int wid = tid >> 6, lane = tid & 63;
  constexpr int NT = INNER/32;   // 32 K-tiles

  __shared__ short At[2][128*32];
  __shared__ short Bt[2][128*32];

  const int srow = lane >> 2;
  const int scol = (lane & 3) * 8;

  const size_t abase = (ROUTED ? (size_t)e*TPE : (size_t)0) + m0;
  const unsigned short* a0 = act + (abase + wid*32 + srow)*(size_t)INNER + scol;
  const unsigned short* a1 = a0 + 16*(size_t)INNER;
  const unsigned short* W2e = W2T + (size_t)e * DIM * INNER;
  const unsigned short* b0 = W2e + ((size_t)(n0 + wid*32 + srow))*INNER + scol;
  const unsigned short* b1 = b0 + 16*(size_t)INNER;

  const int wr = wid >> 1, wc = wid & 1;
  const int lr = lane & 15, kg = (lane >> 4) * 8;

  f32x4 acc[4][4];
  #pragma unroll
  for (int i=0;i<4;i++){
    #pragma unroll
    for (int j=0;j<4;j++) acc[i][j] = (f32x4)0.0f;
  }

  auto stage = [&](int bsel, int t){
    int kb = t*32;
    gload16(a0 + kb, &At[bsel][(wid*2+0)*512]);
    gload16(a1 + kb, &At[bsel][(wid*2+1)*512]);
    gload16(b0 + kb, &Bt[bsel][(wid*2+0)*512]);
    gload16(b1 + kb, &Bt[bsel][(wid*2+1)*512]);
  };
  auto comp = [&](int bsel){
    s16x8 af[4], bf_[4];
    #pragma unroll
    for (int mi=0;mi<4;mi++) af[mi]  = *reinterpret_cast<const s16x8*>(&At[bsel][(wr*64+mi*16+lr)*32 + kg]);
    #pragma unroll
    for (int ni=0;ni<4;ni++) bf_[ni] = *reinterpret_cast<const s16x8*>(&Bt[bsel][(wc*64+ni*16+lr)*32 + kg]);
    #pragma unroll
    for (int mi=0;mi<4;mi++){
      #pragma unroll
      for (int ni=0;ni<4;ni++)
        acc[mi][ni] = __builtin_amdgcn_mfma_f32_16x16x32_bf16(af[mi], bf_[ni], acc[mi][ni], 0, 0, 0);
    }
  };

  stage(0, 0);
  __syncthreads();
  for (int t = 0; t + 2 <= NT - 1; t += 2){
    stage(1, t+1); comp(0); __syncthreads();
    stage(0, t+2); comp(1); __syncthreads();
  }
  stage(1, NT-1); comp(0); __syncthreads();
  comp(1);

  if (ROUTED){
    #pragma unroll
    for (int mi=0;mi<4;mi++){
      #pragma unroll
      for (int r=0;r<4;r++){
        int slot = m0 + wr*64 + mi*16 + (lane>>4)*4 + r;   // 0..1023 within expert
        int b = slot >> 9;
        int gs = (e*BS + b)*CAP + (slot & (CAP-1));
        int t = tok_idx[gs];
        size_t orow = (size_t)b*SLEN + t;
        float gn = gate_raw[gs] / (token_sums[orow] + 1e-12f);  // ROUTE_SCALE = 1
        #pragma unroll
        for (int ni=0;ni<4;ni++){
          int col = n0 + wc*64 + ni*16 + lr;
          atomicAdd(&out[orow*DIM + col], acc[mi][ni][r]*gn);
        }
      }
    }
  } else {
    #pragma unroll
    for (int mi=0;mi<4;mi++){
      #pragma unroll
      for (int r=0;r<4;r++){
        size_t row = (size_t)(m0 + wr*64 + mi*16 + (lane>>4)*4 + r);
        #pragma unroll
        for (int ni=0;ni<4;ni++){
          int col = n0 + wc*64 + ni*16 + lr;
          out[row*DIM + col] = acc[mi][ni][r];
        }
      }
    }
  }
}

extern "C" void kernel_launch(void* const* d_in, const int* in_sizes, int n_in,
                              void* d_out, int out_size, void* d_ws, size_t ws_size,
                              hipStream_t stream) {
  (void)in_sizes; (void)n_in; (void)out_size; (void)ws_size;
  const float* hidden   = (const float*)d_in[0];
  const float* xu       = (const float*)d_in[1];
  const float* timestep = (const float*)d_in[2];
  const float* gate_w   = (const float*)d_in[3];
  const float* gup      = (const float*)d_in[4];
  const float* dwn      = (const float*)d_in[5];
  const float* shin     = (const float*)d_in[6];
  const float* shout    = (const float*)d_in[7];
  float* out = (float*)d_out;

  char* base = (char*)d_ws;
  size_t off = 0;
  auto alloc = [&](size_t bytes)->char*{
    char* p = base + off; off = (off + bytes + 255) & ~(size_t)255; return p;
  };
  float* token_sums = (float*)alloc((size_t)NTOK*4);
  float* tpart      = (float*)alloc((size_t)BS*NEXP*4);
  float* scores     = (float*)alloc((size_t)BS*NEXP*SLEN*4);
  int*   tok_idx    = (int*)  alloc((size_t)NEXP*BS*CAP*4);
  float* gate_raw   = (float*)alloc((size_t)NEXP*BS*CAP*4);
  unsigned short* hid_bf = (unsigned short*)alloc((size_t)NTOK*DIM*2);
  unsigned short* gupT   = (unsigned short*)alloc((size_t)NEXP*2*INNER*DIM*2);
  unsigned short* dwnT   = (unsigned short*)alloc((size_t)NEXP*DIM*INNER*2);
  unsigned short* shinT  = (unsigned short*)alloc((size_t)2*INNER*DIM*2);
  unsigned short* shoutT = (unsigned short*)alloc((size_t)DIM*INNER*2);
  unsigned short* act_s  = (unsigned short*)alloc((size_t)NTOK*INNER*2);
  unsigned short* act_r  = (unsigned short*)alloc((size_t)NEXP*TPE*INNER*2);

  hipMemsetAsync(token_sums, 0, (size_t)NTOK*4, stream);
  cast_kernel<<<(NTOK*DIM)/2048, 256, 0, stream>>>(hidden, hid_bf, (long)NTOK*DIM);
  // weight transposes: out[n][k] = w[k][n], cast to bf16
  transpose_cast_kernel<<<dim3((2*INNER)/32, DIM/32, NEXP), dim3(32,8), 0, stream>>>(gup, gupT, DIM, 2*INNER);
  transpose_cast_kernel<<<dim3(DIM/32, INNER/32, NEXP), dim3(32,8), 0, stream>>>(dwn, dwnT, INNER, DIM);
  transpose_cast_kernel<<<dim3((2*INNER)/32, DIM/32, 1), dim3(32,8), 0, stream>>>(shin, shinT, DIM, 2*INNER);
  transpose_cast_kernel<<<dim3(DIM/32, INNER/32, 1), dim3(32,8), 0, stream>>>(shout, shoutT, INNER, DIM);

  tpart_kernel<<<BS*NEXP, 256, 0, stream>>>(timestep, gate_w, tpart);
  router_kernel<<<NTOK, 256, 0, stream>>>(xu, gate_w, tpart, scores);
  topk_kernel<<<BS*NEXP, 1024, 0, stream>>>(scores, tok_idx, gate_raw, token_sums);

  // shared expert: h = x@W; act = hid * silu(gate)  (silu on SECOND half)
  gemm1_kernel<false,false><<<dim3(INNER/64, NTOK/128, 1), 256, 0, stream>>>(hid_bf, shinT, nullptr, act_s);
  // routed experts: act = silu(g) * u  (silu on FIRST half), gathered rows
  gemm1_kernel<true,true><<<dim3(INNER/64, TPE/128, NEXP), 256, 0, stream>>>(hid_bf, gupT, tok_idx, act_r);

  // shared out: plain store (initializes every element of d_out)
  gemm2_kernel<false><<<dim3(DIM/128, NTOK/128, 1), 256, 0, stream>>>(act_s, shoutT, nullptr, nullptr, nullptr, out);
  // routed out: scale by normalized gate, atomicAdd on top
  gemm2_kernel<true><<<dim3(DIM/128, TPE/128, NEXP), 256, 0, stream>>>(act_r, dwnT, tok_idx, gate_raw, token_sums, out);
}

// Round 4
// 850.633 us; speedup vs baseline: 1.3343x; 1.3343x over previous
//
#include <hip/hip_runtime.h>
#include <hip/hip_bf16.h>
#include <cstdint>
#include <cstddef>

#define BS 2
#define SLEN 4096
#define DIM 2048
#define INNER 1024
#define NEXP 16
#define CAP 512
#define TPE (BS*CAP)      // 1024 tokens per expert
#define NTOK (BS*SLEN)    // 8192

typedef __attribute__((ext_vector_type(4))) float f32x4;
typedef __attribute__((ext_vector_type(8))) short s16x8;

static __device__ __forceinline__ unsigned short f2bf(float f){
  unsigned u = __float_as_uint(f);
  u += 0x7FFFu + ((u >> 16) & 1u);   // RNE
  return (unsigned short)(u >> 16);
}
static __device__ __forceinline__ float sigmoidf_(float x){ return 1.0f/(1.0f+expf(-x)); }

static __device__ __forceinline__ void gload16(const unsigned short* g, short* l){
  __builtin_amdgcn_global_load_lds(
      (const __attribute__((address_space(1))) void*)g,
      (__attribute__((address_space(3))) void*)l, 16, 0, 0);
}

// ---------------- cast fp32 -> bf16 (vectorized) ----------------
__global__ __launch_bounds__(256) void cast_kernel(const float* __restrict__ in,
    unsigned short* __restrict__ out, long n){
  long i = ((long)blockIdx.x*256 + threadIdx.x)*8;
  if (i >= n) return;
  f32x4 a = *reinterpret_cast<const f32x4*>(in+i);
  f32x4 b = *reinterpret_cast<const f32x4*>(in+i+4);
  s16x8 o;
  o[0]=(short)f2bf(a[0]); o[1]=(short)f2bf(a[1]); o[2]=(short)f2bf(a[2]); o[3]=(short)f2bf(a[3]);
  o[4]=(short)f2bf(b[0]); o[5]=(short)f2bf(b[1]); o[6]=(short)f2bf(b[2]); o[7]=(short)f2bf(b[3]);
  *reinterpret_cast<s16x8*>(out+i) = o;
}

// ------------- transpose + cast: in (R x C) fp32 -> out (C x R) bf16 -------------
__global__ __launch_bounds__(256) void transpose_cast_kernel(const float* __restrict__ in,
    unsigned short* __restrict__ out, int R, int C){
  __shared__ float tile[32][33];
  const size_t mat = blockIdx.z;
  const float* src = in + mat*(size_t)R*C;
  unsigned short* dst = out + mat*(size_t)R*C;
  int c0 = blockIdx.x*32, r0 = blockIdx.y*32;
  int tx = threadIdx.x, ty = threadIdx.y;
  #pragma unroll
  for (int i=0;i<32;i+=8)
    tile[ty+i][tx] = src[(size_t)(r0+ty+i)*C + (c0+tx)];
  __syncthreads();
  #pragma unroll
  for (int i=0;i<32;i+=8)
    dst[(size_t)(c0+ty+i)*R + (r0+tx)] = f2bf(tile[tx][ty+i]);
}

// ---------------- timestep part of router logits: tpart[b][e] ----------------
__global__ __launch_bounds__(256) void tpart_kernel(const float* __restrict__ timestep,
    const float* __restrict__ gate_w, float* __restrict__ tpart){
  int b = blockIdx.x >> 4, e = blockIdx.x & 15;
  float acc = 0.f;
  for (int d = threadIdx.x; d < DIM; d += 256)
    acc += timestep[b*DIM + d] * gate_w[(size_t)d*NEXP + e];
  #pragma unroll
  for (int o=32;o>0;o>>=1) acc += __shfl_down(acc, o);
  __shared__ float red[4];
  int lane = threadIdx.x & 63, wid = threadIdx.x >> 6;
  if (lane==0) red[wid] = acc;
  __syncthreads();
  if (threadIdx.x==0) tpart[blockIdx.x] = red[0]+red[1]+red[2]+red[3];
}

// ---------------- router: scores[b][e][s] = sigmoid(logit), fp32 ----------------
__global__ __launch_bounds__(256) void router_kernel(const float* __restrict__ xu,
    const float* __restrict__ gate_w, const float* __restrict__ tpart,
    float* __restrict__ scores){
  const int tok = blockIdx.x;
  const int b = tok >> 12;
  const int s = tok & (SLEN-1);
  const float* xr = xu + (size_t)tok*DIM;
  const int d0 = threadIdx.x * 8;
  f32x4 x0 = *reinterpret_cast<const f32x4*>(xr + d0);
  f32x4 x1 = *reinterpret_cast<const f32x4*>(xr + d0 + 4);
  float p[NEXP];
  #pragma unroll
  for (int e=0;e<NEXP;e++) p[e]=0.f;
  #pragma unroll
  for (int j=0;j<8;j++){
    float xv = (j<4) ? x0[j] : x1[j-4];
    const float* gw = gate_w + (size_t)(DIM + d0 + j)*NEXP;
    f32x4 g0 = *reinterpret_cast<const f32x4*>(gw);
    f32x4 g1 = *reinterpret_cast<const f32x4*>(gw+4);
    f32x4 g2 = *reinterpret_cast<const f32x4*>(gw+8);
    f32x4 g3 = *reinterpret_cast<const f32x4*>(gw+12);
    #pragma unroll
    for (int e=0;e<4;e++){ p[e]+=xv*g0[e]; p[4+e]+=xv*g1[e]; p[8+e]+=xv*g2[e]; p[12+e]+=xv*g3[e]; }
  }
  #pragma unroll
  for (int e=0;e<NEXP;e++){
    float v = p[e];
    #pragma unroll
    for (int o=32;o>0;o>>=1) v += __shfl_down(v, o);
    p[e] = v;
  }
  __shared__ float red[4][NEXP];
  int lane = threadIdx.x & 63, wid = threadIdx.x >> 6;
  if (lane==0){
    #pragma unroll
    for (int e=0;e<NEXP;e++) red[wid][e] = p[e];
  }
  __syncthreads();
  if (threadIdx.x < NEXP){
    int e = threadIdx.x;
    float v = red[0][e]+red[1][e]+red[2][e]+red[3][e] + tpart[b*NEXP+e];
    scores[((size_t)(b*NEXP+e))*SLEN + s] = sigmoidf_(v);
  }
}

// ---------------- top-512 per (b,e) via bitonic sort in LDS ----------------
__global__ __launch_bounds__(1024) void topk_kernel(const float* __restrict__ scores,
    int* __restrict__ tok_idx, float* __restrict__ gate_raw, float* __restrict__ token_sums){
  __shared__ unsigned long long keys[SLEN];
  const int b = blockIdx.x >> 4, e = blockIdx.x & 15;
  const float* sc = scores + (size_t)blockIdx.x * SLEN;
  for (int i = threadIdx.x; i < SLEN; i += 1024){
    unsigned bits = __float_as_uint(sc[i]);
    keys[i] = ((unsigned long long)bits << 32) | (unsigned)(SLEN-1-i);
  }
  __syncthreads();
  for (int k = 2; k <= SLEN; k <<= 1){
    for (int j = k >> 1; j > 0; j >>= 1){
      for (int i = threadIdx.x; i < SLEN; i += 1024){
        int ixj = i ^ j;
        if (ixj > i){
          bool up = ((i & k) == 0);
          unsigned long long a = keys[i], c = keys[ixj];
          if ((a > c) == up){ keys[i] = c; keys[ixj] = a; }
        }
      }
      __syncthreads();
    }
  }
  for (int c = threadIdx.x; c < CAP; c += 1024){
    unsigned long long kk = keys[SLEN-1-c];
    int s = (SLEN-1) - (int)(kk & 0xFFFFFFFFull);
    float g = __uint_as_float((unsigned)(kk >> 32));
    int slot = (e*BS + b)*CAP + c;
    tok_idx[slot]  = s;
    gate_raw[slot] = g;
    atomicAdd(&token_sums[b*SLEN + s], g);
  }
}

// ================= 8-phase 256-tile GEMM (m201 template, plain HIP) ===============
// BM=256, virtual BN=256, BK=64, 8 waves (2M x 4N), per-wave C = 128x64.
// LDS 128KB: A[2][256*64] + B[2][256*64] bf16, st_16x32 swizzle via
// pre-swizzled global source (linear gload_lds dest) + XOR'd ds_read addr.
// Schedule per iteration (computes K-tiles t=buf0, t+1=buf1):
//   P1: ldA(mi0-3,b0) ldB(ni0-1,b0) | stage Ah0(t+1)->b1 | MFMA Q(0,0)
//   P2: ldB(ni2-3,b0)               | stage Ah1(t+1)->b1 | MFMA Q(0,2)
//   P3: ldA(mi4-7,b0)               | stage Bh0(t+2)->b0 | MFMA Q(4,2)
//   P4:                             | stage Bh1(t+2)->b0 | MFMA Q(4,0) vmcnt(4)
//   P5-P8: same on buf1 with stages Ah(t+2)->b0, Bh(t+3)->b1, vmcnt(4) at P8.
// Each phase: [ds_reads; stage; s_barrier; lgkmcnt(0); setprio(1); MFMAs;
// setprio(0); (vmcnt(4));  s_barrier].  vmcnt never drained to 0 in-loop (T4).

#define PH_OPEN() \
  __builtin_amdgcn_s_barrier(); \
  asm volatile("s_waitcnt lgkmcnt(0)" ::: "memory"); \
  __builtin_amdgcn_sched_barrier(0); \
  __builtin_amdgcn_s_setprio(1);

#define PH_CLOSE() \
  __builtin_amdgcn_s_setprio(0); \
  __builtin_amdgcn_sched_barrier(0); \
  __builtin_amdgcn_s_barrier();

#define PH_CLOSE_VM() \
  __builtin_amdgcn_s_setprio(0); \
  __builtin_amdgcn_sched_barrier(0); \
  asm volatile("s_waitcnt vmcnt(4)" ::: "memory"); \
  __builtin_amdgcn_sched_barrier(0); \
  __builtin_amdgcn_s_barrier();

template<int MIB, int NIB>
static __device__ __forceinline__ void mmaQ(f32x4 (&acc)[8][4],
    const s16x8 (&af)[4][2], const s16x8 (&bf)[4][2]){
  #pragma unroll
  for (int i=0;i<4;i++)
    #pragma unroll
    for (int n=0;n<2;n++)
      #pragma unroll
      for (int k=0;k<2;k++)
        acc[MIB+i][NIB+n] = __builtin_amdgcn_mfma_f32_16x16x32_bf16(
            af[i][k], bf[NIB+n][k], acc[MIB+i][NIB+n], 0, 0, 0);
}

template<bool GLU, bool GATHER, bool ROUTED, bool SILU_FIRST, int K>
__global__ __launch_bounds__(512) void gemm8_kernel(
    const unsigned short* __restrict__ A,
    const unsigned short* __restrict__ B,
    size_t bstride,
    const int* __restrict__ tok_idx,
    const float* __restrict__ gate_raw,
    const float* __restrict__ token_sums,
    unsigned short* __restrict__ actOut,
    float* __restrict__ fOut)
{
  constexpr int NT = K/64;
  const int e = blockIdx.z;
  const int tid = threadIdx.x;
  const int lane = tid & 63, w = tid >> 6;        // 8 waves
  const int wr = w >> 2, wc = w & 3;              // 2M x 4N
  const int lr = lane & 15, lg = lane >> 4;
  const int m0 = blockIdx.y * 256;
  const int c0 = blockIdx.x * (GLU ? 128 : 256);

  __shared__ short Ab[2][16384];   // [buf][256 rows x 64 k] (swizzled storage)
  __shared__ short Bb[2][16384];

  // ---- staging source pointers (pre-swizzled global source, rule #21) ----
  // chunk = w*2+j (1KB each); lane l covers row chunk*8 + (l>>3), 16B at col
  // 8*(l&7), XOR'd by 16 shorts for lanes >=32 (st_16x32 inverse on source).
  const int srow8 = lane >> 3;
  const int scol  = (8*(lane & 7)) ^ ((lane >= 32) ? 16 : 0);
  const unsigned short* pA[2][2];
  const unsigned short* pB[2];
  #pragma unroll
  for (int h = 0; h < 2; ++h){
    #pragma unroll
    for (int j = 0; j < 2; ++j){
      int v = h*128 + w*16 + j*8 + srow8;          // virtual A row 0..255
      long garow;
      if (GLU && GATHER){
        int idx = m0 + v;
        int b = idx >> 9;
        int t = tok_idx[(e*BS + b)*CAP + (idx & (CAP-1))];
        garow = (long)b*SLEN + t;
      } else {
        garow = (ROUTED ? (long)e*TPE : 0L) + m0 + v;
      }
      pA[h][j] = A + (size_t)garow*K + scol;
    }
    int v = h*128 + w*16 + srow8;                  // j=0 row; j=1 = +8 (same q block)
    long brow;
    if (GLU) brow = (long)(((v>>4)&1)*INNER + c0 + ((v>>5)*16) + (v & 15));
    else     brow = (long)(c0 + v);
    pB[h] = B + (size_t)e*bstride + (size_t)brow*K + scol;
  }

  auto stageA = [&](int tb, int h){
    short* d = &Ab[tb][h*8192 + w*1024];
    gload16(pA[h][0], d);
    gload16(pA[h][1], d + 512);
    pA[h][0] += 64; pA[h][1] += 64;
  };
  auto stageB = [&](int tb, int h){
    short* d = &Bb[tb][h*8192 + w*1024];
    gload16(pB[h], d);
    gload16(pB[h] + (size_t)8*K, d + 512);   // j=1 row is +8 source rows
    pB[h] += 64;
  };

  // ---- ds_read fragment bases (swizzle: XOR 16 shorts when lr&4) ----
  const int swz = (lr & 4) ? 16 : 0;
  const int aBase = (((128*wr + lr)*64) + lg*8) ^ swz;
  const int bBase = (((64*wc + lr)*64) + lg*8) ^ swz;

  s16x8 af[4][2], bf[4][2];
  f32x4 acc[8][4];
  #pragma unroll
  for (int i=0;i<8;i++)
    #pragma unroll
    for (int j=0;j<4;j++) acc[i][j] = (f32x4)0.0f;

  auto ldA4 = [&](int tb, int mib){
    #pragma unroll
    for (int i=0;i<4;i++)
      #pragma unroll
      for (int k=0;k<2;k++)
        af[i][k] = *reinterpret_cast<const s16x8*>(&Ab[tb][aBase + (mib+i)*1024 + k*32]);
  };
  auto ldB2 = [&](int tb, int nib){
    #pragma unroll
    for (int n=0;n<2;n++)
      #pragma unroll
      for (int k=0;k<2;k++)
        bf[nib+n][k] = *reinterpret_cast<const s16x8*>(&Bb[tb][bBase + (nib+n)*1024 + k*32]);
  };

  // ---- prologue: B(0), A(0) -> buf0; B(1) -> buf1; allow B(1) in flight ----
  stageB(0,0); stageB(0,1); stageA(0,0); stageA(0,1); stageB(1,0); stageB(1,1);
  asm volatile("s_waitcnt vmcnt(4)" ::: "memory");
  __builtin_amdgcn_sched_barrier(0);
  __builtin_amdgcn_s_barrier();

  #pragma unroll 1
  for (int it = 0; it < NT/2; ++it){
    // phases 1-4: compute buf0
    ldA4(0,0); ldB2(0,0); stageA(1,0);
    PH_OPEN(); mmaQ<0,0>(acc, af, bf); PH_CLOSE();
    ldB2(0,2); stageA(1,1);
    PH_OPEN(); mmaQ<0,2>(acc, af, bf); PH_CLOSE();
    ldA4(0,4); stageB(0,0);
    PH_OPEN(); mmaQ<4,2>(acc, af, bf); PH_CLOSE();
    stageB(0,1);
    PH_OPEN(); mmaQ<4,0>(acc, af, bf); PH_CLOSE_VM();
    // phases 5-8: compute buf1
    ldA4(1,0); ldB2(1,0); stageA(0,0);
    PH_OPEN(); mmaQ<0,0>(acc, af, bf); PH_CLOSE();
    ldB2(1,2); stageA(0,1);
    PH_OPEN(); mmaQ<0,2>(acc, af, bf); PH_CLOSE();
    ldA4(1,4); stageB(1,0);
    PH_OPEN(); mmaQ<4,2>(acc, af, bf); PH_CLOSE();
    stageB(1,1);
    PH_OPEN(); mmaQ<4,0>(acc, af, bf); PH_CLOSE_VM();
  }
  asm volatile("s_waitcnt vmcnt(0)" ::: "memory");

  // ---- epilogue ----
  if (GLU){
    const size_t rowbase = GATHER ? (size_t)e*TPE : (size_t)0;
    #pragma unroll
    for (int mi=0; mi<8; mi++){
      int row = m0 + 128*wr + 16*mi + 4*lg;
      #pragma unroll
      for (int p=0;p<2;p++){
        int col = c0 + 32*wc + 16*p + lr;
        #pragma unroll
        for (int r=0;r<4;r++){
          float g = acc[mi][2*p][r], u = acc[mi][2*p+1][r];
          float a = SILU_FIRST ? (g*sigmoidf_(g))*u : g*(u*sigmoidf_(u));
          actOut[(rowbase + row + r)*(size_t)INNER + col] = f2bf(a);
        }
      }
    }
  } else if (ROUTED){
    #pragma unroll
    for (int mi=0; mi<8; mi++){
      #pragma unroll
      for (int r=0;r<4;r++){
        int slot = m0 + 128*wr + 16*mi + 4*lg + r;
        int b = slot >> 9;
        int gs = (e*BS + b)*CAP + (slot & (CAP-1));
        int t = tok_idx[gs];
        size_t orow = (size_t)b*SLEN + t;
        float gn = gate_raw[gs] / (token_sums[orow] + 1e-12f);
        #pragma unroll
        for (int ni=0;ni<4;ni++){
          int col = c0 + 64*wc + 16*ni + lr;
          atomicAdd(&fOut[orow*DIM + col], acc[mi][ni][r]*gn);
        }
      }
    }
  } else {
    #pragma unroll
    for (int mi=0; mi<8; mi++){
      #pragma unroll
      for (int r=0;r<4;r++){
        size_t row = (size_t)(m0 + 128*wr + 16*mi + 4*lg + r);
        #pragma unroll
        for (int ni=0;ni<4;ni++){
          int col = c0 + 64*wc + 16*ni + lr;
          fOut[row*DIM + col] = acc[mi][ni][r];
        }
      }
    }
  }
}

extern "C" void kernel_launch(void* const* d_in, const int* in_sizes, int n_in,
                              void* d_out, int out_size, void* d_ws, size_t ws_size,
                              hipStream_t stream) {
  (void)in_sizes; (void)n_in; (void)out_size; (void)ws_size;
  const float* hidden   = (const float*)d_in[0];
  const float* xu       = (const float*)d_in[1];
  const float* timestep = (const float*)d_in[2];
  const float* gate_w   = (const float*)d_in[3];
  const float* gup      = (const float*)d_in[4];
  const float* dwn      = (const float*)d_in[5];
  const float* shin     = (const float*)d_in[6];
  const float* shout    = (const float*)d_in[7];
  float* out = (float*)d_out;

  char* base = (char*)d_ws;
  size_t off = 0;
  auto alloc = [&](size_t bytes)->char*{
    char* p = base + off; off = (off + bytes + 255) & ~(size_t)255; return p;
  };
  float* token_sums = (float*)alloc((size_t)NTOK*4);
  float* tpart      = (float*)alloc((size_t)BS*NEXP*4);
  float* scores     = (float*)alloc((size_t)BS*NEXP*SLEN*4);
  int*   tok_idx    = (int*)  alloc((size_t)NEXP*BS*CAP*4);
  float* gate_raw   = (float*)alloc((size_t)NEXP*BS*CAP*4);
  unsigned short* hid_bf = (unsigned short*)alloc((size_t)NTOK*DIM*2);
  unsigned short* gupT   = (unsigned short*)alloc((size_t)NEXP*2*INNER*DIM*2);
  unsigned short* dwnT   = (unsigned short*)alloc((size_t)NEXP*DIM*INNER*2);
  unsigned short* shinT  = (unsigned short*)alloc((size_t)2*INNER*DIM*2);
  unsigned short* shoutT = (unsigned short*)alloc((size_t)DIM*INNER*2);
  unsigned short* act_s  = (unsigned short*)alloc((size_t)NTOK*INNER*2);
  unsigned short* act_r  = (unsigned short*)alloc((size_t)NEXP*TPE*INNER*2);
  (void)alloc(1<<16);   // pad: staging prefetch overruns up to ~256B per row

  hipMemsetAsync(token_sums, 0, (size_t)NTOK*4, stream);
  cast_kernel<<<(NTOK*DIM)/2048, 256, 0, stream>>>(hidden, hid_bf, (long)NTOK*DIM);
  transpose_cast_kernel<<<dim3((2*INNER)/32, DIM/32, NEXP), dim3(32,8), 0, stream>>>(gup, gupT, DIM, 2*INNER);
  transpose_cast_kernel<<<dim3(DIM/32, INNER/32, NEXP), dim3(32,8), 0, stream>>>(dwn, dwnT, INNER, DIM);
  transpose_cast_kernel<<<dim3((2*INNER)/32, DIM/32, 1), dim3(32,8), 0, stream>>>(shin, shinT, DIM, 2*INNER);
  transpose_cast_kernel<<<dim3(DIM/32, INNER/32, 1), dim3(32,8), 0, stream>>>(shout, shoutT, INNER, DIM);

  tpart_kernel<<<BS*NEXP, 256, 0, stream>>>(timestep, gate_w, tpart);
  router_kernel<<<NTOK, 256, 0, stream>>>(xu, gate_w, tpart, scores);
  topk_kernel<<<BS*NEXP, 1024, 0, stream>>>(scores, tok_idx, gate_raw, token_sums);

  // gemm1 shared: act_s = h0 * silu(h1)   (GLU, no gather, silu on SECOND half)
  gemm8_kernel<true,false,false,false,DIM><<<dim3(INNER/128, NTOK/256, 1), 512, 0, stream>>>(
      hid_bf, shinT, 0, nullptr, nullptr, nullptr, act_s, nullptr);
  // gemm1 routed: act_r = silu(g) * u     (GLU, gather, silu on FIRST half)
  gemm8_kernel<true,true,false,true,DIM><<<dim3(INNER/128, TPE/256, NEXP), 512, 0, stream>>>(
      hid_bf, gupT, (size_t)(2*INNER)*DIM, tok_idx, nullptr, nullptr, act_r, nullptr);
  // gemm2 shared: out = act_s @ shoutT (plain store initializes d_out)
  gemm8_kernel<false,false,false,false,INNER><<<dim3(DIM/256, NTOK/256, 1), 512, 0, stream>>>(
      act_s, shoutT, 0, nullptr, nullptr, nullptr, nullptr, out);
  // gemm2 routed: atomicAdd(out, acc * gate/(sums+eps))
  gemm8_kernel<false,false,true,false,INNER><<<dim3(DIM/256, TPE/256, NEXP), 512, 0, stream>>>(
      act_r, dwnT, (size_t)DIM*INNER, tok_idx, gate_raw, token_sums, nullptr, out);
}

// Round 5
// 813.863 us; speedup vs baseline: 1.3946x; 1.0452x over previous
//
#include <hip/hip_runtime.h>
#include <hip/hip_bf16.h>
#include <cstdint>
#include <cstddef>

#define BS 2
#define SLEN 4096
#define DIM 2048
#define INNER 1024
#define NEXP 16
#define CAP 512
#define TPE (BS*CAP)      // 1024 tokens per expert
#define NTOK (BS*SLEN)    // 8192

typedef __attribute__((ext_vector_type(4))) float f32x4;
typedef __attribute__((ext_vector_type(8))) short s16x8;

static __device__ __forceinline__ unsigned short f2bf(float f){
  unsigned u = __float_as_uint(f);
  u += 0x7FFFu + ((u >> 16) & 1u);   // RNE
  return (unsigned short)(u >> 16);
}
static __device__ __forceinline__ float sigmoidf_(float x){ return 1.0f/(1.0f+expf(-x)); }

static __device__ __forceinline__ void gload16(const unsigned short* g, short* l){
  __builtin_amdgcn_global_load_lds(
      (const __attribute__((address_space(1))) void*)g,
      (__attribute__((address_space(3))) void*)l, 16, 0, 0);
}

// ---------------- cast fp32 -> bf16 (vectorized) ----------------
__global__ __launch_bounds__(256) void cast_kernel(const float* __restrict__ in,
    unsigned short* __restrict__ out, long n){
  long i = ((long)blockIdx.x*256 + threadIdx.x)*8;
  if (i >= n) return;
  f32x4 a = *reinterpret_cast<const f32x4*>(in+i);
  f32x4 b = *reinterpret_cast<const f32x4*>(in+i+4);
  s16x8 o;
  o[0]=(short)f2bf(a[0]); o[1]=(short)f2bf(a[1]); o[2]=(short)f2bf(a[2]); o[3]=(short)f2bf(a[3]);
  o[4]=(short)f2bf(b[0]); o[5]=(short)f2bf(b[1]); o[6]=(short)f2bf(b[2]); o[7]=(short)f2bf(b[3]);
  *reinterpret_cast<s16x8*>(out+i) = o;
}

// ------------- transpose + cast: in (R x C) fp32 -> out (C x R) bf16 -------------
__global__ __launch_bounds__(256) void transpose_cast_kernel(const float* __restrict__ in,
    unsigned short* __restrict__ out, int R, int C){
  __shared__ float tile[32][33];
  const size_t mat = blockIdx.z;
  const float* src = in + mat*(size_t)R*C;
  unsigned short* dst = out + mat*(size_t)R*C;
  int c0 = blockIdx.x*32, r0 = blockIdx.y*32;
  int tx = threadIdx.x, ty = threadIdx.y;
  #pragma unroll
  for (int i=0;i<32;i+=8)
    tile[ty+i][tx] = src[(size_t)(r0+ty+i)*C + (c0+tx)];
  __syncthreads();
  #pragma unroll
  for (int i=0;i<32;i+=8)
    dst[(size_t)(c0+ty+i)*R + (r0+tx)] = f2bf(tile[tx][ty+i]);
}

// -------- fp32 transpose of gate_w hidden half: gwT[e][d] = gate_w[DIM+d][e] --------
__global__ __launch_bounds__(256) void gwT_kernel(const float* __restrict__ gate_w,
    float* __restrict__ gwT){
  int d = blockIdx.x*256 + threadIdx.x;    // 8 blocks x 256 = 2048 dims
  #pragma unroll
  for (int e=0;e<NEXP;e++)
    gwT[(size_t)e*DIM + d] = gate_w[(size_t)(DIM+d)*NEXP + e];
}

// ---------------- timestep part of router logits: tpart[b][e] ----------------
__global__ __launch_bounds__(256) void tpart_kernel(const float* __restrict__ timestep,
    const float* __restrict__ gate_w, float* __restrict__ tpart){
  int b = blockIdx.x >> 4, e = blockIdx.x & 15;
  float acc = 0.f;
  for (int d = threadIdx.x; d < DIM; d += 256)
    acc += timestep[b*DIM + d] * gate_w[(size_t)d*NEXP + e];
  #pragma unroll
  for (int o=32;o>0;o>>=1) acc += __shfl_down(acc, o);
  __shared__ float red[4];
  int lane = threadIdx.x & 63, wid = threadIdx.x >> 6;
  if (lane==0) red[wid] = acc;
  __syncthreads();
  if (threadIdx.x==0) tpart[blockIdx.x] = red[0]+red[1]+red[2]+red[3];
}

// ------- router v2: lane = (token_sub, expert); full-K dot per lane, no reduce -------
// grid 512 blocks x 256 thr; wave = 4 tokens x 16 experts. x-loads broadcast
// across e-lanes; gwT rows L1-resident. scores[b*16+e][s] fp32.
__global__ __launch_bounds__(256) void router2_kernel(const float* __restrict__ xu,
    const float* __restrict__ gwT, const float* __restrict__ tpart,
    float* __restrict__ scores){
  const int lane = threadIdx.x & 63, wv = threadIdx.x >> 6;
  const int tsub = lane >> 4, e = lane & 15;
  const int tok = blockIdx.x*16 + wv*4 + tsub;
  const int b = tok >> 12, s = tok & (SLEN-1);
  const float* xr = xu + (size_t)tok*DIM;
  const float* gr = gwT + (size_t)e*DIM;
  float a0=0.f, a1=0.f, a2=0.f, a3=0.f;
  for (int k = 0; k < DIM; k += 16){
    f32x4 x0 = *reinterpret_cast<const f32x4*>(xr+k);
    f32x4 x1 = *reinterpret_cast<const f32x4*>(xr+k+4);
    f32x4 x2 = *reinterpret_cast<const f32x4*>(xr+k+8);
    f32x4 x3 = *reinterpret_cast<const f32x4*>(xr+k+12);
    f32x4 g0 = *reinterpret_cast<const f32x4*>(gr+k);
    f32x4 g1 = *reinterpret_cast<const f32x4*>(gr+k+4);
    f32x4 g2 = *reinterpret_cast<const f32x4*>(gr+k+8);
    f32x4 g3 = *reinterpret_cast<const f32x4*>(gr+k+12);
    a0 += x0[0]*g0[0] + x0[1]*g0[1] + x0[2]*g0[2] + x0[3]*g0[3];
    a1 += x1[0]*g1[0] + x1[1]*g1[1] + x1[2]*g1[2] + x1[3]*g1[3];
    a2 += x2[0]*g2[0] + x2[1]*g2[1] + x2[2]*g2[2] + x2[3]*g2[3];
    a3 += x3[0]*g3[0] + x3[1]*g3[1] + x3[2]*g3[2] + x3[3]*g3[3];
  }
  float v = (a0+a1)+(a2+a3) + tpart[b*NEXP+e];
  scores[((size_t)(b*NEXP+e))*SLEN + s] = sigmoidf_(v);
}

// ---------------- top-512 per (b,e) via bitonic sort in LDS ----------------
__global__ __launch_bounds__(1024) void topk_kernel(const float* __restrict__ scores,
    int* __restrict__ tok_idx, float* __restrict__ gate_raw, float* __restrict__ token_sums){
  __shared__ unsigned long long keys[SLEN];
  const int b = blockIdx.x >> 4, e = blockIdx.x & 15;
  const float* sc = scores + (size_t)blockIdx.x * SLEN;
  for (int i = threadIdx.x; i < SLEN; i += 1024){
    unsigned bits = __float_as_uint(sc[i]);
    keys[i] = ((unsigned long long)bits << 32) | (unsigned)(SLEN-1-i);
  }
  __syncthreads();
  for (int k = 2; k <= SLEN; k <<= 1){
    for (int j = k >> 1; j > 0; j >>= 1){
      for (int i = threadIdx.x; i < SLEN; i += 1024){
        int ixj = i ^ j;
        if (ixj > i){
          bool up = ((i & k) == 0);
          unsigned long long a = keys[i], c = keys[ixj];
          if ((a > c) == up){ keys[i] = c; keys[ixj] = a; }
        }
      }
      __syncthreads();
    }
  }
  for (int c = threadIdx.x; c < CAP; c += 1024){
    unsigned long long kk = keys[SLEN-1-c];
    int s = (SLEN-1) - (int)(kk & 0xFFFFFFFFull);
    float g = __uint_as_float((unsigned)(kk >> 32));
    int slot = (e*BS + b)*CAP + c;
    tok_idx[slot]  = s;
    gate_raw[slot] = g;
    atomicAdd(&token_sums[b*SLEN + s], g);
  }
}

// ================= 8-phase 256-tile GEMM (m201 template, plain HIP) ===============
// BM=256, virtual BN=256, BK=64, 8 waves (2M x 4N), per-wave C = 128x64.

#define PH_OPEN() \
  __builtin_amdgcn_s_barrier(); \
  asm volatile("s_waitcnt lgkmcnt(0)" ::: "memory"); \
  __builtin_amdgcn_sched_barrier(0); \
  __builtin_amdgcn_s_setprio(1);

#define PH_CLOSE() \
  __builtin_amdgcn_s_setprio(0); \
  __builtin_amdgcn_sched_barrier(0); \
  __builtin_amdgcn_s_barrier();

#define PH_CLOSE_VM() \
  __builtin_amdgcn_s_setprio(0); \
  __builtin_amdgcn_sched_barrier(0); \
  asm volatile("s_waitcnt vmcnt(4)" ::: "memory"); \
  __builtin_amdgcn_sched_barrier(0); \
  __builtin_amdgcn_s_barrier();

template<int MIB, int NIB>
static __device__ __forceinline__ void mmaQ(f32x4 (&acc)[8][4],
    const s16x8 (&af)[4][2], const s16x8 (&bf)[4][2]){
  #pragma unroll
  for (int i=0;i<4;i++)
    #pragma unroll
    for (int n=0;n<2;n++)
      #pragma unroll
      for (int k=0;k<2;k++)
        acc[MIB+i][NIB+n] = __builtin_amdgcn_mfma_f32_16x16x32_bf16(
            af[i][k], bf[NIB+n][k], acc[MIB+i][NIB+n], 0, 0, 0);
}

template<bool GLU, bool GATHER, bool ROUTED, bool SILU_FIRST, int K>
__global__ __launch_bounds__(512) void gemm8_kernel(
    const unsigned short* __restrict__ A,
    const unsigned short* __restrict__ B,
    size_t bstride,
    const int* __restrict__ tok_idx,
    const float* __restrict__ gate_raw,
    const float* __restrict__ token_sums,
    unsigned short* __restrict__ actOut,
    float* __restrict__ fOut)
{
  constexpr int NT = K/64;
  const int e = blockIdx.z;
  const int tid = threadIdx.x;
  const int lane = tid & 63, w = tid >> 6;        // 8 waves
  const int wr = w >> 2, wc = w & 3;              // 2M x 4N
  const int lr = lane & 15, lg = lane >> 4;
  const int m0 = blockIdx.y * 256;
  const int c0 = blockIdx.x * (GLU ? 128 : 256);

  __shared__ short Ab[2][16384];   // [buf][256 rows x 64 k] (swizzled storage)
  __shared__ short Bb[2][16384];

  const int srow8 = lane >> 3;
  const int scol  = (8*(lane & 7)) ^ ((lane >= 32) ? 16 : 0);
  const unsigned short* pA[2][2];
  const unsigned short* pB[2];
  #pragma unroll
  for (int h = 0; h < 2; ++h){
    #pragma unroll
    for (int j = 0; j < 2; ++j){
      int v = h*128 + w*16 + j*8 + srow8;          // virtual A row 0..255
      long garow;
      if (GLU && GATHER){
        int idx = m0 + v;
        int b = idx >> 9;
        int t = tok_idx[(e*BS + b)*CAP + (idx & (CAP-1))];
        garow = (long)b*SLEN + t;
      } else {
        garow = (ROUTED ? (long)e*TPE : 0L) + m0 + v;
      }
      pA[h][j] = A + (size_t)garow*K + scol;
    }
    int v = h*128 + w*16 + srow8;
    long brow;
    if (GLU) brow = (long)(((v>>4)&1)*INNER + c0 + ((v>>5)*16) + (v & 15));
    else     brow = (long)(c0 + v);
    pB[h] = B + (size_t)e*bstride + (size_t)brow*K + scol;
  }

  auto stageA = [&](int tb, int h){
    short* d = &Ab[tb][h*8192 + w*1024];
    gload16(pA[h][0], d);
    gload16(pA[h][1], d + 512);
    pA[h][0] += 64; pA[h][1] += 64;
  };
  auto stageB = [&](int tb, int h){
    short* d = &Bb[tb][h*8192 + w*1024];
    gload16(pB[h], d);
    gload16(pB[h] + (size_t)8*K, d + 512);
    pB[h] += 64;
  };

  const int swz = (lr & 4) ? 16 : 0;
  const int aBase = (((128*wr + lr)*64) + lg*8) ^ swz;
  const int bBase = (((64*wc + lr)*64) + lg*8) ^ swz;

  s16x8 af[4][2], bf[4][2];
  f32x4 acc[8][4];
  #pragma unroll
  for (int i=0;i<8;i++)
    #pragma unroll
    for (int j=0;j<4;j++) acc[i][j] = (f32x4)0.0f;

  auto ldA4 = [&](int tb, int mib){
    #pragma unroll
    for (int i=0;i<4;i++)
      #pragma unroll
      for (int k=0;k<2;k++)
        af[i][k] = *reinterpret_cast<const s16x8*>(&Ab[tb][aBase + (mib+i)*1024 + k*32]);
  };
  auto ldB2 = [&](int tb, int nib){
    #pragma unroll
    for (int n=0;n<2;n++)
      #pragma unroll
      for (int k=0;k<2;k++)
        bf[nib+n][k] = *reinterpret_cast<const s16x8*>(&Bb[tb][bBase + (nib+n)*1024 + k*32]);
  };

  stageB(0,0); stageB(0,1); stageA(0,0); stageA(0,1); stageB(1,0); stageB(1,1);
  asm volatile("s_waitcnt vmcnt(4)" ::: "memory");
  __builtin_amdgcn_sched_barrier(0);
  __builtin_amdgcn_s_barrier();

  #pragma unroll 1
  for (int it = 0; it < NT/2; ++it){
    ldA4(0,0); ldB2(0,0); stageA(1,0);
    PH_OPEN(); mmaQ<0,0>(acc, af, bf); PH_CLOSE();
    ldB2(0,2); stageA(1,1);
    PH_OPEN(); mmaQ<0,2>(acc, af, bf); PH_CLOSE();
    ldA4(0,4); stageB(0,0);
    PH_OPEN(); mmaQ<4,2>(acc, af, bf); PH_CLOSE();
    stageB(0,1);
    PH_OPEN(); mmaQ<4,0>(acc, af, bf); PH_CLOSE_VM();
    ldA4(1,0); ldB2(1,0); stageA(0,0);
    PH_OPEN(); mmaQ<0,0>(acc, af, bf); PH_CLOSE();
    ldB2(1,2); stageA(0,1);
    PH_OPEN(); mmaQ<0,2>(acc, af, bf); PH_CLOSE();
    ldA4(1,4); stageB(1,0);
    PH_OPEN(); mmaQ<4,2>(acc, af, bf); PH_CLOSE();
    stageB(1,1);
    PH_OPEN(); mmaQ<4,0>(acc, af, bf); PH_CLOSE_VM();
  }
  asm volatile("s_waitcnt vmcnt(0)" ::: "memory");

  if (GLU){
    const size_t rowbase = GATHER ? (size_t)e*TPE : (size_t)0;
    #pragma unroll
    for (int mi=0; mi<8; mi++){
      int row = m0 + 128*wr + 16*mi + 4*lg;
      #pragma unroll
      for (int p=0;p<2;p++){
        int col = c0 + 32*wc + 16*p + lr;
        #pragma unroll
        for (int r=0;r<4;r++){
          float g = acc[mi][2*p][r], u = acc[mi][2*p+1][r];
          float a = SILU_FIRST ? (g*sigmoidf_(g))*u : g*(u*sigmoidf_(u));
          actOut[(rowbase + row + r)*(size_t)INNER + col] = f2bf(a);
        }
      }
    }
  } else if (ROUTED){
    #pragma unroll
    for (int mi=0; mi<8; mi++){
      #pragma unroll
      for (int r=0;r<4;r++){
        int slot = m0 + 128*wr + 16*mi + 4*lg + r;
        int b = slot >> 9;
        int gs = (e*BS + b)*CAP + (slot & (CAP-1));
        int t = tok_idx[gs];
        size_t orow = (size_t)b*SLEN + t;
        float gn = gate_raw[gs] / (token_sums[orow] + 1e-12f);
        #pragma unroll
        for (int ni=0;ni<4;ni++){
          int col = c0 + 64*wc + 16*ni + lr;
          atomicAdd(&fOut[orow*DIM + col], acc[mi][ni][r]*gn);
        }
      }
    }
  } else {
    #pragma unroll
    for (int mi=0; mi<8; mi++){
      #pragma unroll
      for (int r=0;r<4;r++){
        size_t row = (size_t)(m0 + 128*wr + 16*mi + 4*lg + r);
        #pragma unroll
        for (int ni=0;ni<4;ni++){
          int col = c0 + 64*wc + 16*ni + lr;
          fOut[row*DIM + col] = acc[mi][ni][r];
        }
      }
    }
  }
}

extern "C" void kernel_launch(void* const* d_in, const int* in_sizes, int n_in,
                              void* d_out, int out_size, void* d_ws, size_t ws_size,
                              hipStream_t stream) {
  (void)in_sizes; (void)n_in; (void)out_size; (void)ws_size;
  const float* hidden   = (const float*)d_in[0];
  const float* xu       = (const float*)d_in[1];
  const float* timestep = (const float*)d_in[2];
  const float* gate_w   = (const float*)d_in[3];
  const float* gup      = (const float*)d_in[4];
  const float* dwn      = (const float*)d_in[5];
  const float* shin     = (const float*)d_in[6];
  const float* shout    = (const float*)d_in[7];
  float* out = (float*)d_out;

  char* base = (char*)d_ws;
  size_t off = 0;
  auto alloc = [&](size_t bytes)->char*{
    char* p = base + off; off = (off + bytes + 255) & ~(size_t)255; return p;
  };
  float* token_sums = (float*)alloc((size_t)NTOK*4);
  float* tpart      = (float*)alloc((size_t)BS*NEXP*4);
  float* gwT        = (float*)alloc((size_t)NEXP*DIM*4);
  float* scores     = (float*)alloc((size_t)BS*NEXP*SLEN*4);
  int*   tok_idx    = (int*)  alloc((size_t)NEXP*BS*CAP*4);
  float* gate_raw   = (float*)alloc((size_t)NEXP*BS*CAP*4);
  unsigned short* hid_bf = (unsigned short*)alloc((size_t)NTOK*DIM*2);
  unsigned short* gupT   = (unsigned short*)alloc((size_t)NEXP*2*INNER*DIM*2);
  unsigned short* dwnT   = (unsigned short*)alloc((size_t)NEXP*DIM*INNER*2);
  unsigned short* shinT  = (unsigned short*)alloc((size_t)2*INNER*DIM*2);
  unsigned short* shoutT = (unsigned short*)alloc((size_t)DIM*INNER*2);
  unsigned short* act_s  = (unsigned short*)alloc((size_t)NTOK*INNER*2);
  unsigned short* act_r  = (unsigned short*)alloc((size_t)NEXP*TPE*INNER*2);
  (void)alloc(1<<16);   // pad: staging prefetch overruns up to ~256B per row

  hipMemsetAsync(token_sums, 0, (size_t)NTOK*4, stream);
  cast_kernel<<<(NTOK*DIM)/2048, 256, 0, stream>>>(hidden, hid_bf, (long)NTOK*DIM);
  transpose_cast_kernel<<<dim3((2*INNER)/32, DIM/32, NEXP), dim3(32,8), 0, stream>>>(gup, gupT, DIM, 2*INNER);
  transpose_cast_kernel<<<dim3(DIM/32, INNER/32, NEXP), dim3(32,8), 0, stream>>>(dwn, dwnT, INNER, DIM);
  transpose_cast_kernel<<<dim3((2*INNER)/32, DIM/32, 1), dim3(32,8), 0, stream>>>(shin, shinT, DIM, 2*INNER);
  transpose_cast_kernel<<<dim3(DIM/32, INNER/32, 1), dim3(32,8), 0, stream>>>(shout, shoutT, INNER, DIM);

  gwT_kernel<<<DIM/256, 256, 0, stream>>>(gate_w, gwT);
  tpart_kernel<<<BS*NEXP, 256, 0, stream>>>(timestep, gate_w, tpart);
  router2_kernel<<<NTOK/16, 256, 0, stream>>>(xu, gwT, tpart, scores);
  topk_kernel<<<BS*NEXP, 1024, 0, stream>>>(scores, tok_idx, gate_raw, token_sums);

  // gemm1 shared: act_s = h0 * silu(h1)   (GLU, no gather, silu on SECOND half)
  gemm8_kernel<true,false,false,false,DIM><<<dim3(INNER/128, NTOK/256, 1), 512, 0, stream>>>(
      hid_bf, shinT, 0, nullptr, nullptr, nullptr, act_s, nullptr);
  // gemm1 routed: act_r = silu(g) * u     (GLU, gather, silu on FIRST half)
  gemm8_kernel<true,true,false,true,DIM><<<dim3(INNER/128, TPE/256, NEXP), 512, 0, stream>>>(
      hid_bf, gupT, (size_t)(2*INNER)*DIM, tok_idx, nullptr, nullptr, act_r, nullptr);
  // gemm2 shared: out = act_s @ shoutT (plain store initializes d_out)
  gemm8_kernel<false,false,false,false,INNER><<<dim3(DIM/256, NTOK/256, 1), 512, 0, stream>>>(
      act_s, shoutT, 0, nullptr, nullptr, nullptr, nullptr, out);
  // gemm2 routed: atomicAdd(out, acc * gate/(sums+eps))
  gemm8_kernel<false,false,true,false,INNER><<<dim3(DIM/256, TPE/256, NEXP), 512, 0, stream>>>(
      act_r, dwnT, (size_t)DIM*INNER, tok_idx, gate_raw, token_sums, nullptr, out);
}

// Round 6
// 789.993 us; speedup vs baseline: 1.4367x; 1.0302x over previous
//
#include <hip/hip_runtime.h>
#include <hip/hip_bf16.h>
#include <cstdint>
#include <cstddef>

#define BS 2
#define SLEN 4096
#define DIM 2048
#define INNER 1024
#define NEXP 16
#define CAP 512
#define TPE (BS*CAP)      // 1024 tokens per expert
#define NTOK (BS*SLEN)    // 8192

typedef __attribute__((ext_vector_type(4))) float f32x4;
typedef __attribute__((ext_vector_type(8))) short s16x8;

static __device__ __forceinline__ unsigned short f2bf(float f){
  unsigned u = __float_as_uint(f);
  u += 0x7FFFu + ((u >> 16) & 1u);   // RNE
  return (unsigned short)(u >> 16);
}
static __device__ __forceinline__ float sigmoidf_(float x){ return 1.0f/(1.0f+expf(-x)); }

static __device__ __forceinline__ void gload16(const unsigned short* g, short* l){
  __builtin_amdgcn_global_load_lds(
      (const __attribute__((address_space(1))) void*)g,
      (__attribute__((address_space(3))) void*)l, 16, 0, 0);
}

// ---------------- cast fp32 -> bf16 (vectorized) ----------------
__global__ __launch_bounds__(256) void cast_kernel(const float* __restrict__ in,
    unsigned short* __restrict__ out, long n){
  long i = ((long)blockIdx.x*256 + threadIdx.x)*8;
  if (i >= n) return;
  f32x4 a = *reinterpret_cast<const f32x4*>(in+i);
  f32x4 b = *reinterpret_cast<const f32x4*>(in+i+4);
  s16x8 o;
  o[0]=(short)f2bf(a[0]); o[1]=(short)f2bf(a[1]); o[2]=(short)f2bf(a[2]); o[3]=(short)f2bf(a[3]);
  o[4]=(short)f2bf(b[0]); o[5]=(short)f2bf(b[1]); o[6]=(short)f2bf(b[2]); o[7]=(short)f2bf(b[3]);
  *reinterpret_cast<s16x8*>(out+i) = o;
}

// ------------- transpose + cast: in (R x C) fp32 -> out (C x R) bf16 -------------
__global__ __launch_bounds__(256) void transpose_cast_kernel(const float* __restrict__ in,
    unsigned short* __restrict__ out, int R, int C){
  __shared__ float tile[32][33];
  const size_t mat = blockIdx.z;
  const float* src = in + mat*(size_t)R*C;
  unsigned short* dst = out + mat*(size_t)R*C;
  int c0 = blockIdx.x*32, r0 = blockIdx.y*32;
  int tx = threadIdx.x, ty = threadIdx.y;
  #pragma unroll
  for (int i=0;i<32;i+=8)
    tile[ty+i][tx] = src[(size_t)(r0+ty+i)*C + (c0+tx)];
  __syncthreads();
  #pragma unroll
  for (int i=0;i<32;i+=8)
    dst[(size_t)(c0+ty+i)*R + (r0+tx)] = f2bf(tile[tx][ty+i]);
}

// -------- fp32 transpose of gate_w hidden half: gwT[e][d] = gate_w[DIM+d][e] --------
__global__ __launch_bounds__(256) void gwT_kernel(const float* __restrict__ gate_w,
    float* __restrict__ gwT){
  int d = blockIdx.x*256 + threadIdx.x;    // 8 blocks x 256 = 2048 dims
  #pragma unroll
  for (int e=0;e<NEXP;e++)
    gwT[(size_t)e*DIM + d] = gate_w[(size_t)(DIM+d)*NEXP + e];
}

// ---------------- timestep part of router logits: tpart[b][e] ----------------
__global__ __launch_bounds__(256) void tpart_kernel(const float* __restrict__ timestep,
    const float* __restrict__ gate_w, float* __restrict__ tpart){
  int b = blockIdx.x >> 4, e = blockIdx.x & 15;
  float acc = 0.f;
  for (int d = threadIdx.x; d < DIM; d += 256)
    acc += timestep[b*DIM + d] * gate_w[(size_t)d*NEXP + e];
  #pragma unroll
  for (int o=32;o>0;o>>=1) acc += __shfl_down(acc, o);
  __shared__ float red[4];
  int lane = threadIdx.x & 63, wid = threadIdx.x >> 6;
  if (lane==0) red[wid] = acc;
  __syncthreads();
  if (threadIdx.x==0) tpart[blockIdx.x] = red[0]+red[1]+red[2]+red[3];
}

// ------- router v2: lane = (token_sub, expert); full-K dot per lane, no reduce -------
__global__ __launch_bounds__(256) void router2_kernel(const float* __restrict__ xu,
    const float* __restrict__ gwT, const float* __restrict__ tpart,
    float* __restrict__ scores){
  const int lane = threadIdx.x & 63, wv = threadIdx.x >> 6;
  const int tsub = lane >> 4, e = lane & 15;
  const int tok = blockIdx.x*16 + wv*4 + tsub;
  const int b = tok >> 12, s = tok & (SLEN-1);
  const float* xr = xu + (size_t)tok*DIM;
  const float* gr = gwT + (size_t)e*DIM;
  float a0=0.f, a1=0.f, a2=0.f, a3=0.f;
  for (int k = 0; k < DIM; k += 16){
    f32x4 x0 = *reinterpret_cast<const f32x4*>(xr+k);
    f32x4 x1 = *reinterpret_cast<const f32x4*>(xr+k+4);
    f32x4 x2 = *reinterpret_cast<const f32x4*>(xr+k+8);
    f32x4 x3 = *reinterpret_cast<const f32x4*>(xr+k+12);
    f32x4 g0 = *reinterpret_cast<const f32x4*>(gr+k);
    f32x4 g1 = *reinterpret_cast<const f32x4*>(gr+k+4);
    f32x4 g2 = *reinterpret_cast<const f32x4*>(gr+k+8);
    f32x4 g3 = *reinterpret_cast<const f32x4*>(gr+k+12);
    a0 += x0[0]*g0[0] + x0[1]*g0[1] + x0[2]*g0[2] + x0[3]*g0[3];
    a1 += x1[0]*g1[0] + x1[1]*g1[1] + x1[2]*g1[2] + x1[3]*g1[3];
    a2 += x2[0]*g2[0] + x2[1]*g2[1] + x2[2]*g2[2] + x2[3]*g2[3];
    a3 += x3[0]*g3[0] + x3[1]*g3[1] + x3[2]*g3[2] + x3[3]*g3[3];
  }
  float v = (a0+a1)+(a2+a3) + tpart[b*NEXP+e];
  scores[((size_t)(b*NEXP+e))*SLEN + s] = sigmoidf_(v);
}

// ---------------- top-512 per (b,e) via bitonic sort in LDS ----------------
__global__ __launch_bounds__(1024) void topk_kernel(const float* __restrict__ scores,
    int* __restrict__ tok_idx, float* __restrict__ gate_raw, float* __restrict__ token_sums){
  __shared__ unsigned long long keys[SLEN];
  const int b = blockIdx.x >> 4, e = blockIdx.x & 15;
  const float* sc = scores + (size_t)blockIdx.x * SLEN;
  for (int i = threadIdx.x; i < SLEN; i += 1024){
    unsigned bits = __float_as_uint(sc[i]);
    keys[i] = ((unsigned long long)bits << 32) | (unsigned)(SLEN-1-i);
  }
  __syncthreads();
  for (int k = 2; k <= SLEN; k <<= 1){
    for (int j = k >> 1; j > 0; j >>= 1){
      for (int i = threadIdx.x; i < SLEN; i += 1024){
        int ixj = i ^ j;
        if (ixj > i){
          bool up = ((i & k) == 0);
          unsigned long long a = keys[i], c = keys[ixj];
          if ((a > c) == up){ keys[i] = c; keys[ixj] = a; }
        }
      }
      __syncthreads();
    }
  }
  for (int c = threadIdx.x; c < CAP; c += 1024){
    unsigned long long kk = keys[SLEN-1-c];
    int s = (SLEN-1) - (int)(kk & 0xFFFFFFFFull);
    float g = __uint_as_float((unsigned)(kk >> 32));
    int slot = (e*BS + b)*CAP + c;
    tok_idx[slot]  = s;
    gate_raw[slot] = g;
    atomicAdd(&token_sums[b*SLEN + s], g);
  }
}

// ================= 8-phase 256-tile GEMM (m201 template, plain HIP) ===============
// BM=256, virtual BN=256, BK=64, 8 waves (2M x 4N), per-wave C = 128x64.
// LDS swizzle (G4 full 8-slot): 16B col-slot ^= (row&7), pre-swizzled global
// source (linear gload_lds dest) + XOR'd ds_read slot. Involution verified:
// LDS[r][cs] holds global slot cs^(r&7); read of slot s touches cs=s^(r&7).

#define PH_OPEN() \
  __builtin_amdgcn_s_barrier(); \
  asm volatile("s_waitcnt lgkmcnt(0)" ::: "memory"); \
  __builtin_amdgcn_sched_barrier(0); \
  __builtin_amdgcn_s_setprio(1);

#define PH_CLOSE() \
  __builtin_amdgcn_s_setprio(0); \
  __builtin_amdgcn_sched_barrier(0); \
  __builtin_amdgcn_s_barrier();

#define PH_CLOSE_VM() \
  __builtin_amdgcn_s_setprio(0); \
  __builtin_amdgcn_sched_barrier(0); \
  asm volatile("s_waitcnt vmcnt(4)" ::: "memory"); \
  __builtin_amdgcn_sched_barrier(0); \
  __builtin_amdgcn_s_barrier();

template<int MIB, int NIB>
static __device__ __forceinline__ void mmaQ(f32x4 (&acc)[8][4],
    const s16x8 (&af)[4][2], const s16x8 (&bf)[4][2]){
  #pragma unroll
  for (int i=0;i<4;i++)
    #pragma unroll
    for (int n=0;n<2;n++)
      #pragma unroll
      for (int k=0;k<2;k++)
        acc[MIB+i][NIB+n] = __builtin_amdgcn_mfma_f32_16x16x32_bf16(
            af[i][k], bf[NIB+n][k], acc[MIB+i][NIB+n], 0, 0, 0);
}

template<bool GLU, bool GATHER, bool ROUTED, bool SILU_FIRST, int K>
__global__ __launch_bounds__(512) void gemm8_kernel(
    const unsigned short* __restrict__ A,
    const unsigned short* __restrict__ B,
    size_t bstride,
    const int* __restrict__ tok_idx,
    const float* __restrict__ gate_raw,
    const float* __restrict__ token_sums,
    unsigned short* __restrict__ actOut,
    float* __restrict__ fOut)
{
  constexpr int NT = K/64;
  const int e = blockIdx.z;
  const int tid = threadIdx.x;
  const int lane = tid & 63, w = tid >> 6;        // 8 waves
  const int wr = w >> 2, wc = w & 3;              // 2M x 4N
  const int lr = lane & 15, lg = lane >> 4;
  const int m0 = blockIdx.y * 256;
  const int c0 = blockIdx.x * (GLU ? 128 : 256);

  __shared__ short Ab[2][16384];   // [buf][256 rows x 64 k] (swizzled storage)
  __shared__ short Bb[2][16384];

  // ---- staging source (pre-swizzled): lane l -> LDS row rr=l>>3, slot l&7;
  // content must be global slot (l&7) ^ rr  (slot = 16B = 8 shorts)
  const int srow8 = lane >> 3;
  const int scol  = 8 * ((lane & 7) ^ srow8);
  const unsigned short* pA[2][2];
  const unsigned short* pB[2];
  #pragma unroll
  for (int h = 0; h < 2; ++h){
    #pragma unroll
    for (int j = 0; j < 2; ++j){
      int v = h*128 + w*16 + j*8 + srow8;          // virtual A row 0..255
      long garow;
      if (GLU && GATHER){
        int idx = m0 + v;
        int b = idx >> 9;
        int t = tok_idx[(e*BS + b)*CAP + (idx & (CAP-1))];
        garow = (long)b*SLEN + t;
      } else {
        garow = (ROUTED ? (long)e*TPE : 0L) + m0 + v;
      }
      pA[h][j] = A + (size_t)garow*K + scol;
    }
    int v = h*128 + w*16 + srow8;
    long brow;
    if (GLU) brow = (long)(((v>>4)&1)*INNER + c0 + ((v>>5)*16) + (v & 15));
    else     brow = (long)(c0 + v);
    pB[h] = B + (size_t)e*bstride + (size_t)brow*K + scol;
  }

  auto stageA = [&](int tb, int h){
    short* d = &Ab[tb][h*8192 + w*1024];
    gload16(pA[h][0], d);
    gload16(pA[h][1], d + 512);
    pA[h][0] += 64; pA[h][1] += 64;
  };
  auto stageB = [&](int tb, int h){
    short* d = &Bb[tb][h*8192 + w*1024];
    gload16(pB[h], d);
    gload16(pB[h] + (size_t)8*K, d + 512);
    pB[h] += 64;
  };

  // ---- ds_read: row r, global slot s -> LDS slot s ^ (r&7); k toggles slot bit2 (XOR)
  const int swzr  = (lr & 7) * 8;                  // shorts
  const int aRow  = (128*wr + lr)*64;
  const int bRow  = (64*wc + lr)*64;
  const int slot0 = (lg*8) ^ swzr;                 // k=0 slot offset (shorts)

  s16x8 af[4][2], bf[4][2];
  f32x4 acc[8][4];
  #pragma unroll
  for (int i=0;i<8;i++)
    #pragma unroll
    for (int j=0;j<4;j++) acc[i][j] = (f32x4)0.0f;

  auto ldA4 = [&](int tb, int mib){
    #pragma unroll
    for (int i=0;i<4;i++)
      #pragma unroll
      for (int k=0;k<2;k++)
        af[i][k] = *reinterpret_cast<const s16x8*>(&Ab[tb][aRow + (mib+i)*1024 + (slot0 ^ (k*32))]);
  };
  auto ldB2 = [&](int tb, int nib){
    #pragma unroll
    for (int n=0;n<2;n++)
      #pragma unroll
      for (int k=0;k<2;k++)
        bf[nib+n][k] = *reinterpret_cast<const s16x8*>(&Bb[tb][bRow + (nib+n)*1024 + (slot0 ^ (k*32))]);
  };

  stageB(0,0); stageB(0,1); stageA(0,0); stageA(0,1); stageB(1,0); stageB(1,1);
  asm volatile("s_waitcnt vmcnt(4)" ::: "memory");
  __builtin_amdgcn_sched_barrier(0);
  __builtin_amdgcn_s_barrier();

  #pragma unroll 1
  for (int it = 0; it < NT/2; ++it){
    ldA4(0,0); ldB2(0,0); stageA(1,0);
    PH_OPEN(); mmaQ<0,0>(acc, af, bf); PH_CLOSE();
    ldB2(0,2); stageA(1,1);
    PH_OPEN(); mmaQ<0,2>(acc, af, bf); PH_CLOSE();
    ldA4(0,4); stageB(0,0);
    PH_OPEN(); mmaQ<4,2>(acc, af, bf); PH_CLOSE();
    stageB(0,1);
    PH_OPEN(); mmaQ<4,0>(acc, af, bf); PH_CLOSE_VM();
    ldA4(1,0); ldB2(1,0); stageA(0,0);
    PH_OPEN(); mmaQ<0,0>(acc, af, bf); PH_CLOSE();
    ldB2(1,2); stageA(0,1);
    PH_OPEN(); mmaQ<0,2>(acc, af, bf); PH_CLOSE();
    ldA4(1,4); stageB(1,0);
    PH_OPEN(); mmaQ<4,2>(acc, af, bf); PH_CLOSE();
    stageB(1,1);
    PH_OPEN(); mmaQ<4,0>(acc, af, bf); PH_CLOSE_VM();
  }
  asm volatile("s_waitcnt vmcnt(0)" ::: "memory");

  if (GLU){
    const size_t rowbase = GATHER ? (size_t)e*TPE : (size_t)0;
    #pragma unroll
    for (int mi=0; mi<8; mi++){
      int row = m0 + 128*wr + 16*mi + 4*lg;
      #pragma unroll
      for (int p=0;p<2;p++){
        int col = c0 + 32*wc + 16*p + lr;
        #pragma unroll
        for (int r=0;r<4;r++){
          float g = acc[mi][2*p][r], u = acc[mi][2*p+1][r];
          float a = SILU_FIRST ? (g*sigmoidf_(g))*u : g*(u*sigmoidf_(u));
          actOut[(rowbase + row + r)*(size_t)INNER + col] = f2bf(a);
        }
      }
    }
  } else if (ROUTED){
    #pragma unroll
    for (int mi=0; mi<8; mi++){
      #pragma unroll
      for (int r=0;r<4;r++){
        int slot = m0 + 128*wr + 16*mi + 4*lg + r;
        int b = slot >> 9;
        int gs = (e*BS + b)*CAP + (slot & (CAP-1));
        int t = tok_idx[gs];
        size_t orow = (size_t)b*SLEN + t;
        float gn = gate_raw[gs] / (token_sums[orow] + 1e-12f);
        #pragma unroll
        for (int ni=0;ni<4;ni++){
          int col = c0 + 64*wc + 16*ni + lr;
          atomicAdd(&fOut[orow*DIM + col], acc[mi][ni][r]*gn);
        }
      }
    }
  } else {
    #pragma unroll
    for (int mi=0; mi<8; mi++){
      #pragma unroll
      for (int r=0;r<4;r++){
        size_t row = (size_t)(m0 + 128*wr + 16*mi + 4*lg + r);
        #pragma unroll
        for (int ni=0;ni<4;ni++){
          int col = c0 + 64*wc + 16*ni + lr;
          fOut[row*DIM + col] = acc[mi][ni][r];
        }
      }
    }
  }
}

extern "C" void kernel_launch(void* const* d_in, const int* in_sizes, int n_in,
                              void* d_out, int out_size, void* d_ws, size_t ws_size,
                              hipStream_t stream) {
  (void)in_sizes; (void)n_in; (void)out_size; (void)ws_size;
  const float* hidden   = (const float*)d_in[0];
  const float* xu       = (const float*)d_in[1];
  const float* timestep = (const float*)d_in[2];
  const float* gate_w   = (const float*)d_in[3];
  const float* gup      = (const float*)d_in[4];
  const float* dwn      = (const float*)d_in[5];
  const float* shin     = (const float*)d_in[6];
  const float* shout    = (const float*)d_in[7];
  float* out = (float*)d_out;

  char* base = (char*)d_ws;
  size_t off = 0;
  auto alloc = [&](size_t bytes)->char*{
    char* p = base + off; off = (off + bytes + 255) & ~(size_t)255; return p;
  };
  float* token_sums = (float*)alloc((size_t)NTOK*4);
  float* tpart      = (float*)alloc((size_t)BS*NEXP*4);
  float* gwT        = (float*)alloc((size_t)NEXP*DIM*4);
  float* scores     = (float*)alloc((size_t)BS*NEXP*SLEN*4);
  int*   tok_idx    = (int*)  alloc((size_t)NEXP*BS*CAP*4);
  float* gate_raw   = (float*)alloc((size_t)NEXP*BS*CAP*4);
  unsigned short* hid_bf = (unsigned short*)alloc((size_t)NTOK*DIM*2);
  unsigned short* gupT   = (unsigned short*)alloc((size_t)NEXP*2*INNER*DIM*2);
  unsigned short* dwnT   = (unsigned short*)alloc((size_t)NEXP*DIM*INNER*2);
  unsigned short* shinT  = (unsigned short*)alloc((size_t)2*INNER*DIM*2);
  unsigned short* shoutT = (unsigned short*)alloc((size_t)DIM*INNER*2);
  unsigned short* act_s  = (unsigned short*)alloc((size_t)NTOK*INNER*2);
  unsigned short* act_r  = (unsigned short*)alloc((size_t)NEXP*TPE*INNER*2);
  (void)alloc(1<<16);   // pad: staging prefetch overruns up to ~256B per row

  hipMemsetAsync(token_sums, 0, (size_t)NTOK*4, stream);
  cast_kernel<<<(NTOK*DIM)/2048, 256, 0, stream>>>(hidden, hid_bf, (long)NTOK*DIM);
  transpose_cast_kernel<<<dim3((2*INNER)/32, DIM/32, NEXP), dim3(32,8), 0, stream>>>(gup, gupT, DIM, 2*INNER);
  transpose_cast_kernel<<<dim3(DIM/32, INNER/32, NEXP), dim3(32,8), 0, stream>>>(dwn, dwnT, INNER, DIM);
  transpose_cast_kernel<<<dim3((2*INNER)/32, DIM/32, 1), dim3(32,8), 0, stream>>>(shin, shinT, DIM, 2*INNER);
  transpose_cast_kernel<<<dim3(DIM/32, INNER/32, 1), dim3(32,8), 0, stream>>>(shout, shoutT, INNER, DIM);

  gwT_kernel<<<DIM/256, 256, 0, stream>>>(gate_w, gwT);
  tpart_kernel<<<BS*NEXP, 256, 0, stream>>>(timestep, gate_w, tpart);
  router2_kernel<<<NTOK/16, 256, 0, stream>>>(xu, gwT, tpart, scores);
  topk_kernel<<<BS*NEXP, 1024, 0, stream>>>(scores, tok_idx, gate_raw, token_sums);

  // gemm1 shared: act_s = h0 * silu(h1)   (GLU, no gather, silu on SECOND half)
  gemm8_kernel<true,false,false,false,DIM><<<dim3(INNER/128, NTOK/256, 1), 512, 0, stream>>>(
      hid_bf, shinT, 0, nullptr, nullptr, nullptr, act_s, nullptr);
  // gemm1 routed: act_r = silu(g) * u     (GLU, gather, silu on FIRST half)
  gemm8_kernel<true,true,false,true,DIM><<<dim3(INNER/128, TPE/256, NEXP), 512, 0, stream>>>(
      hid_bf, gupT, (size_t)(2*INNER)*DIM, tok_idx, nullptr, nullptr, act_r, nullptr);
  // gemm2 shared: out = act_s @ shoutT (plain store initializes d_out)
  gemm8_kernel<false,false,false,false,INNER><<<dim3(DIM/256, NTOK/256, 1), 512, 0, stream>>>(
      act_s, shoutT, 0, nullptr, nullptr, nullptr, nullptr, out);
  // gemm2 routed: atomicAdd(out, acc * gate/(sums+eps))
  gemm8_kernel<false,false,true,false,INNER><<<dim3(DIM/256, TPE/256, NEXP), 512, 0, stream>>>(
      act_r, dwnT, (size_t)DIM*INNER, tok_idx, gate_raw, token_sums, nullptr, out);
}

// Round 7
// 741.119 us; speedup vs baseline: 1.5315x; 1.0659x over previous
//
#include <hip/hip_runtime.h>
#include <hip/hip_bf16.h>
#include <cstdint>
#include <cstddef>

#define BS 2
#define SLEN 4096
#define DIM 2048
#define INNER 1024
#define NEXP 16
#define CAP 512
#define TPE (BS*CAP)      // 1024 tokens per expert
#define NTOK (BS*SLEN)    // 8192

typedef __attribute__((ext_vector_type(4))) float f32x4;
typedef __attribute__((ext_vector_type(8))) short s16x8;

static __device__ __forceinline__ unsigned short f2bf(float f){
  unsigned u = __float_as_uint(f);
  u += 0x7FFFu + ((u >> 16) & 1u);   // RNE
  return (unsigned short)(u >> 16);
}
static __device__ __forceinline__ float sigmoidf_(float x){ return 1.0f/(1.0f+expf(-x)); }

static __device__ __forceinline__ void gload16(const unsigned short* g, short* l){
  __builtin_amdgcn_global_load_lds(
      (const __attribute__((address_space(1))) void*)g,
      (__attribute__((address_space(3))) void*)l, 16, 0, 0);
}

// ---------------- cast fp32 -> bf16 (vectorized) ----------------
__global__ __launch_bounds__(256) void cast_kernel(const float* __restrict__ in,
    unsigned short* __restrict__ out, long n){
  long i = ((long)blockIdx.x*256 + threadIdx.x)*8;
  if (i >= n) return;
  f32x4 a = *reinterpret_cast<const f32x4*>(in+i);
  f32x4 b = *reinterpret_cast<const f32x4*>(in+i+4);
  s16x8 o;
  o[0]=(short)f2bf(a[0]); o[1]=(short)f2bf(a[1]); o[2]=(short)f2bf(a[2]); o[3]=(short)f2bf(a[3]);
  o[4]=(short)f2bf(b[0]); o[5]=(short)f2bf(b[1]); o[6]=(short)f2bf(b[2]); o[7]=(short)f2bf(b[3]);
  *reinterpret_cast<s16x8*>(out+i) = o;
}

// ------------- transpose + cast: in (R x C) fp32 -> out (C x R) bf16 -------------
__global__ __launch_bounds__(256) void transpose_cast_kernel(const float* __restrict__ in,
    unsigned short* __restrict__ out, int R, int C){
  __shared__ float tile[32][33];
  const size_t mat = blockIdx.z;
  const float* src = in + mat*(size_t)R*C;
  unsigned short* dst = out + mat*(size_t)R*C;
  int c0 = blockIdx.x*32, r0 = blockIdx.y*32;
  int tx = threadIdx.x, ty = threadIdx.y;
  #pragma unroll
  for (int i=0;i<32;i+=8)
    tile[ty+i][tx] = src[(size_t)(r0+ty+i)*C + (c0+tx)];
  __syncthreads();
  #pragma unroll
  for (int i=0;i<32;i+=8)
    dst[(size_t)(c0+ty+i)*R + (r0+tx)] = f2bf(tile[tx][ty+i]);
}

// -------- fp32 transpose of gate_w hidden half: gwT[e][d] = gate_w[DIM+d][e] --------
__global__ __launch_bounds__(256) void gwT_kernel(const float* __restrict__ gate_w,
    float* __restrict__ gwT){
  int d = blockIdx.x*256 + threadIdx.x;    // 8 blocks x 256 = 2048 dims
  #pragma unroll
  for (int e=0;e<NEXP;e++)
    gwT[(size_t)e*DIM + d] = gate_w[(size_t)(DIM+d)*NEXP + e];
}

// ---------------- timestep part of router logits: tpart[b][e] ----------------
__global__ __launch_bounds__(256) void tpart_kernel(const float* __restrict__ timestep,
    const float* __restrict__ gate_w, float* __restrict__ tpart){
  int b = blockIdx.x >> 4, e = blockIdx.x & 15;
  float acc = 0.f;
  for (int d = threadIdx.x; d < DIM; d += 256)
    acc += timestep[b*DIM + d] * gate_w[(size_t)d*NEXP + e];
  #pragma unroll
  for (int o=32;o>0;o>>=1) acc += __shfl_down(acc, o);
  __shared__ float red[4];
  int lane = threadIdx.x & 63, wid = threadIdx.x >> 6;
  if (lane==0) red[wid] = acc;
  __syncthreads();
  if (threadIdx.x==0) tpart[blockIdx.x] = red[0]+red[1]+red[2]+red[3];
}

// ------- router v2: lane = (token_sub, expert); full-K dot per lane, no reduce -------
__global__ __launch_bounds__(256) void router2_kernel(const float* __restrict__ xu,
    const float* __restrict__ gwT, const float* __restrict__ tpart,
    float* __restrict__ scores){
  const int lane = threadIdx.x & 63, wv = threadIdx.x >> 6;
  const int tsub = lane >> 4, e = lane & 15;
  const int tok = blockIdx.x*16 + wv*4 + tsub;
  const int b = tok >> 12, s = tok & (SLEN-1);
  const float* xr = xu + (size_t)tok*DIM;
  const float* gr = gwT + (size_t)e*DIM;
  float a0=0.f, a1=0.f, a2=0.f, a3=0.f;
  for (int k = 0; k < DIM; k += 16){
    f32x4 x0 = *reinterpret_cast<const f32x4*>(xr+k);
    f32x4 x1 = *reinterpret_cast<const f32x4*>(xr+k+4);
    f32x4 x2 = *reinterpret_cast<const f32x4*>(xr+k+8);
    f32x4 x3 = *reinterpret_cast<const f32x4*>(xr+k+12);
    f32x4 g0 = *reinterpret_cast<const f32x4*>(gr+k);
    f32x4 g1 = *reinterpret_cast<const f32x4*>(gr+k+4);
    f32x4 g2 = *reinterpret_cast<const f32x4*>(gr+k+8);
    f32x4 g3 = *reinterpret_cast<const f32x4*>(gr+k+12);
    a0 += x0[0]*g0[0] + x0[1]*g0[1] + x0[2]*g0[2] + x0[3]*g0[3];
    a1 += x1[0]*g1[0] + x1[1]*g1[1] + x1[2]*g1[2] + x1[3]*g1[3];
    a2 += x2[0]*g2[0] + x2[1]*g2[1] + x2[2]*g2[2] + x2[3]*g2[3];
    a3 += x3[0]*g3[0] + x3[1]*g3[1] + x3[2]*g3[2] + x3[3]*g3[3];
  }
  float v = (a0+a1)+(a2+a3) + tpart[b*NEXP+e];
  scores[((size_t)(b*NEXP+e))*SLEN + s] = sigmoidf_(v);
}

// ---------------- top-512 per (b,e) via bitonic sort in LDS ----------------
__global__ __launch_bounds__(1024) void topk_kernel(const float* __restrict__ scores,
    int* __restrict__ tok_idx, float* __restrict__ gate_raw, float* __restrict__ token_sums){
  __shared__ unsigned long long keys[SLEN];
  const int b = blockIdx.x >> 4, e = blockIdx.x & 15;
  const float* sc = scores + (size_t)blockIdx.x * SLEN;
  for (int i = threadIdx.x; i < SLEN; i += 1024){
    unsigned bits = __float_as_uint(sc[i]);
    keys[i] = ((unsigned long long)bits << 32) | (unsigned)(SLEN-1-i);
  }
  __syncthreads();
  for (int k = 2; k <= SLEN; k <<= 1){
    for (int j = k >> 1; j > 0; j >>= 1){
      for (int i = threadIdx.x; i < SLEN; i += 1024){
        int ixj = i ^ j;
        if (ixj > i){
          bool up = ((i & k) == 0);
          unsigned long long a = keys[i], c = keys[ixj];
          if ((a > c) == up){ keys[i] = c; keys[ixj] = a; }
        }
      }
      __syncthreads();
    }
  }
  for (int c = threadIdx.x; c < CAP; c += 1024){
    unsigned long long kk = keys[SLEN-1-c];
    int s = (SLEN-1) - (int)(kk & 0xFFFFFFFFull);
    float g = __uint_as_float((unsigned)(kk >> 32));
    int slot = (e*BS + b)*CAP + c;
    tok_idx[slot]  = s;
    gate_raw[slot] = g;
    atomicAdd(&token_sums[b*SLEN + s], g);
  }
}

// ================= relaxed 4-super-phase 256-tile GEMM ===============
// BM=256, virtual BN=256, BK=64, 8 waves (2M x 4N), per-wave C = 128x64.
// LDS swizzle (G4 full 8-slot): 16B col-slot ^= (row&7), pre-swizzled global
// source + XOR'd ds_read slot. ds_reads are compiler-visible C++ LDS loads ->
// hipcc inserts fine-grained lgkmcnt per MFMA; NO explicit lgkmcnt(0) drain.
// One barrier per super-phase (WAR-derived minimum); vmcnt(4) before the
// barriers that precede reads of freshly-staged buffers (never 0 in-loop).

#define SP_END() \
  __builtin_amdgcn_sched_barrier(0); \
  __builtin_amdgcn_s_barrier();

#define SP_END_VM() \
  __builtin_amdgcn_sched_barrier(0); \
  asm volatile("s_waitcnt vmcnt(4)" ::: "memory"); \
  __builtin_amdgcn_sched_barrier(0); \
  __builtin_amdgcn_s_barrier();

template<int MIB, int NIB>
static __device__ __forceinline__ void mmaQ(f32x4 (&acc)[8][4],
    const s16x8 (&af)[4][2], const s16x8 (&bf)[4][2]){
  #pragma unroll
  for (int i=0;i<4;i++)
    #pragma unroll
    for (int n=0;n<2;n++)
      #pragma unroll
      for (int k=0;k<2;k++)
        acc[MIB+i][NIB+n] = __builtin_amdgcn_mfma_f32_16x16x32_bf16(
            af[i][k], bf[NIB+n][k], acc[MIB+i][NIB+n], 0, 0, 0);
}

template<bool GLU, bool GATHER, bool ROUTED, bool SILU_FIRST, int K>
__global__ __launch_bounds__(512) void gemm8_kernel(
    const unsigned short* __restrict__ A,
    const unsigned short* __restrict__ B,
    size_t bstride,
    const int* __restrict__ tok_idx,
    const float* __restrict__ gate_raw,
    const float* __restrict__ token_sums,
    unsigned short* __restrict__ actOut,
    float* __restrict__ fOut)
{
  constexpr int NT = K/64;
  const int e = blockIdx.z;
  const int tid = threadIdx.x;
  const int lane = tid & 63, w = tid >> 6;        // 8 waves
  const int wr = w >> 2, wc = w & 3;              // 2M x 4N
  const int lr = lane & 15, lg = lane >> 4;
  const int m0 = blockIdx.y * 256;
  const int c0 = blockIdx.x * (GLU ? 128 : 256);

  __shared__ short Ab[2][16384];   // [buf][256 rows x 64 k] (swizzled storage)
  __shared__ short Bb[2][16384];

  // ---- staging source (pre-swizzled): lane l -> LDS row rr=l>>3, slot l&7;
  // content must be global slot (l&7) ^ rr  (slot = 16B = 8 shorts)
  const int srow8 = lane >> 3;
  const int scol  = 8 * ((lane & 7) ^ srow8);
  const unsigned short* pA[2][2];
  const unsigned short* pB[2];
  #pragma unroll
  for (int h = 0; h < 2; ++h){
    #pragma unroll
    for (int j = 0; j < 2; ++j){
      int v = h*128 + w*16 + j*8 + srow8;          // virtual A row 0..255
      long garow;
      if (GLU && GATHER){
        int idx = m0 + v;
        int b = idx >> 9;
        int t = tok_idx[(e*BS + b)*CAP + (idx & (CAP-1))];
        garow = (long)b*SLEN + t;
      } else {
        garow = (ROUTED ? (long)e*TPE : 0L) + m0 + v;
      }
      pA[h][j] = A + (size_t)garow*K + scol;
    }
    int v = h*128 + w*16 + srow8;
    long brow;
    if (GLU) brow = (long)(((v>>4)&1)*INNER + c0 + ((v>>5)*16) + (v & 15));
    else     brow = (long)(c0 + v);
    pB[h] = B + (size_t)e*bstride + (size_t)brow*K + scol;
  }

  auto stageA = [&](int tb, int h){
    short* d = &Ab[tb][h*8192 + w*1024];
    gload16(pA[h][0], d);
    gload16(pA[h][1], d + 512);
    pA[h][0] += 64; pA[h][1] += 64;
  };
  auto stageB = [&](int tb, int h){
    short* d = &Bb[tb][h*8192 + w*1024];
    gload16(pB[h], d);
    gload16(pB[h] + (size_t)8*K, d + 512);
    pB[h] += 64;
  };

  // ---- ds_read: row r, global slot s -> LDS slot s ^ (r&7); k toggles slot bit2 (XOR)
  const int swzr  = (lr & 7) * 8;                  // shorts
  const int aRow  = (128*wr + lr)*64;
  const int bRow  = (64*wc + lr)*64;
  const int slot0 = (lg*8) ^ swzr;                 // k=0 slot offset (shorts)

  s16x8 af[4][2], bf[4][2];
  f32x4 acc[8][4];
  #pragma unroll
  for (int i=0;i<8;i++)
    #pragma unroll
    for (int j=0;j<4;j++) acc[i][j] = (f32x4)0.0f;

  auto ldA4 = [&](int tb, int mib){
    #pragma unroll
    for (int i=0;i<4;i++)
      #pragma unroll
      for (int k=0;k<2;k++)
        af[i][k] = *reinterpret_cast<const s16x8*>(&Ab[tb][aRow + (mib+i)*1024 + (slot0 ^ (k*32))]);
  };
  auto ldB2 = [&](int tb, int nib){
    #pragma unroll
    for (int n=0;n<2;n++)
      #pragma unroll
      for (int k=0;k<2;k++)
        bf[nib+n][k] = *reinterpret_cast<const s16x8*>(&Bb[tb][bRow + (nib+n)*1024 + (slot0 ^ (k*32))]);
  };

  // ---- prologue: B(0),A(0) -> buf0; B(1) -> buf1 left in flight ----
  stageB(0,0); stageB(0,1); stageA(0,0); stageA(0,1); stageB(1,0); stageB(1,1);
  asm volatile("s_waitcnt vmcnt(4)" ::: "memory");
  __builtin_amdgcn_sched_barrier(0);
  __builtin_amdgcn_s_barrier();

  #pragma unroll 1
  for (int it = 0; it < NT/2; ++it){
    // SP1: buf0 A-lo + all B reads; stage A(t+1)->buf1; 32 MFMA
    ldA4(0,0); ldB2(0,0); ldB2(0,2);
    stageA(1,0); stageA(1,1);
    mmaQ<0,0>(acc, af, bf); mmaQ<0,2>(acc, af, bf);
    SP_END();
    // SP2: buf0 A-hi reads; stage B(t+2)->buf0; 32 MFMA; drain A(1)+B(1)prev
    ldA4(0,4);
    stageB(0,0); stageB(0,1);
    mmaQ<4,2>(acc, af, bf); mmaQ<4,0>(acc, af, bf);
    SP_END_VM();
    // SP3: buf1 A-lo + all B reads; stage A(t+2)->buf0; 32 MFMA
    ldA4(1,0); ldB2(1,0); ldB2(1,2);
    stageA(0,0); stageA(0,1);
    mmaQ<0,0>(acc, af, bf); mmaQ<0,2>(acc, af, bf);
    SP_END();
    // SP4: buf1 A-hi reads; stage B(t+3)->buf1; 32 MFMA; drain B(0)+A(0)
    ldA4(1,4);
    stageB(1,0); stageB(1,1);
    mmaQ<4,2>(acc, af, bf); mmaQ<4,0>(acc, af, bf);
    SP_END_VM();
  }
  asm volatile("s_waitcnt vmcnt(0)" ::: "memory");

  if (GLU){
    const size_t rowbase = GATHER ? (size_t)e*TPE : (size_t)0;
    #pragma unroll
    for (int mi=0; mi<8; mi++){
      int row = m0 + 128*wr + 16*mi + 4*lg;
      #pragma unroll
      for (int p=0;p<2;p++){
        int col = c0 + 32*wc + 16*p + lr;
        #pragma unroll
        for (int r=0;r<4;r++){
          float g = acc[mi][2*p][r], u = acc[mi][2*p+1][r];
          float a = SILU_FIRST ? (g*sigmoidf_(g))*u : g*(u*sigmoidf_(u));
          actOut[(rowbase + row + r)*(size_t)INNER + col] = f2bf(a);
        }
      }
    }
  } else if (ROUTED){
    #pragma unroll
    for (int mi=0; mi<8; mi++){
      #pragma unroll
      for (int r=0;r<4;r++){
        int slot = m0 + 128*wr + 16*mi + 4*lg + r;
        int b = slot >> 9;
        int gs = (e*BS + b)*CAP + (slot & (CAP-1));
        int t = tok_idx[gs];
        size_t orow = (size_t)b*SLEN + t;
        float gn = gate_raw[gs] / (token_sums[orow] + 1e-12f);
        #pragma unroll
        for (int ni=0;ni<4;ni++){
          int col = c0 + 64*wc + 16*ni + lr;
          atomicAdd(&fOut[orow*DIM + col], acc[mi][ni][r]*gn);
        }
      }
    }
  } else {
    #pragma unroll
    for (int mi=0; mi<8; mi++){
      #pragma unroll
      for (int r=0;r<4;r++){
        size_t row = (size_t)(m0 + 128*wr + 16*mi + 4*lg + r);
        #pragma unroll
        for (int ni=0;ni<4;ni++){
          int col = c0 + 64*wc + 16*ni + lr;
          fOut[row*DIM + col] = acc[mi][ni][r];
        }
      }
    }
  }
}

extern "C" void kernel_launch(void* const* d_in, const int* in_sizes, int n_in,
                              void* d_out, int out_size, void* d_ws, size_t ws_size,
                              hipStream_t stream) {
  (void)in_sizes; (void)n_in; (void)out_size; (void)ws_size;
  const float* hidden   = (const float*)d_in[0];
  const float* xu       = (const float*)d_in[1];
  const float* timestep = (const float*)d_in[2];
  const float* gate_w   = (const float*)d_in[3];
  const float* gup      = (const float*)d_in[4];
  const float* dwn      = (const float*)d_in[5];
  const float* shin     = (const float*)d_in[6];
  const float* shout    = (const float*)d_in[7];
  float* out = (float*)d_out;

  char* base = (char*)d_ws;
  size_t off = 0;
  auto alloc = [&](size_t bytes)->char*{
    char* p = base + off; off = (off + bytes + 255) & ~(size_t)255; return p;
  };
  float* token_sums = (float*)alloc((size_t)NTOK*4);
  float* tpart      = (float*)alloc((size_t)BS*NEXP*4);
  float* gwT        = (float*)alloc((size_t)NEXP*DIM*4);
  float* scores     = (float*)alloc((size_t)BS*NEXP*SLEN*4);
  int*   tok_idx    = (int*)  alloc((size_t)NEXP*BS*CAP*4);
  float* gate_raw   = (float*)alloc((size_t)NEXP*BS*CAP*4);
  unsigned short* hid_bf = (unsigned short*)alloc((size_t)NTOK*DIM*2);
  unsigned short* gupT   = (unsigned short*)alloc((size_t)NEXP*2*INNER*DIM*2);
  unsigned short* dwnT   = (unsigned short*)alloc((size_t)NEXP*DIM*INNER*2);
  unsigned short* shinT  = (unsigned short*)alloc((size_t)2*INNER*DIM*2);
  unsigned short* shoutT = (unsigned short*)alloc((size_t)DIM*INNER*2);
  unsigned short* act_s  = (unsigned short*)alloc((size_t)NTOK*INNER*2);
  unsigned short* act_r  = (unsigned short*)alloc((size_t)NEXP*TPE*INNER*2);
  (void)alloc(1<<16);   // pad: staging prefetch overruns up to ~256B per row

  hipMemsetAsync(token_sums, 0, (size_t)NTOK*4, stream);
  cast_kernel<<<(NTOK*DIM)/2048, 256, 0, stream>>>(hidden, hid_bf, (long)NTOK*DIM);
  transpose_cast_kernel<<<dim3((2*INNER)/32, DIM/32, NEXP), dim3(32,8), 0, stream>>>(gup, gupT, DIM, 2*INNER);
  transpose_cast_kernel<<<dim3(DIM/32, INNER/32, NEXP), dim3(32,8), 0, stream>>>(dwn, dwnT, INNER, DIM);
  transpose_cast_kernel<<<dim3((2*INNER)/32, DIM/32, 1), dim3(32,8), 0, stream>>>(shin, shinT, DIM, 2*INNER);
  transpose_cast_kernel<<<dim3(DIM/32, INNER/32, 1), dim3(32,8), 0, stream>>>(shout, shoutT, INNER, DIM);

  gwT_kernel<<<DIM/256, 256, 0, stream>>>(gate_w, gwT);
  tpart_kernel<<<BS*NEXP, 256, 0, stream>>>(timestep, gate_w, tpart);
  router2_kernel<<<NTOK/16, 256, 0, stream>>>(xu, gwT, tpart, scores);
  topk_kernel<<<BS*NEXP, 1024, 0, stream>>>(scores, tok_idx, gate_raw, token_sums);

  // gemm1 shared: act_s = h0 * silu(h1)   (GLU, no gather, silu on SECOND half)
  gemm8_kernel<true,false,false,false,DIM><<<dim3(INNER/128, NTOK/256, 1), 512, 0, stream>>>(
      hid_bf, shinT, 0, nullptr, nullptr, nullptr, act_s, nullptr);
  // gemm1 routed: act_r = silu(g) * u     (GLU, gather, silu on FIRST half)
  gemm8_kernel<true,true,false,true,DIM><<<dim3(INNER/128, TPE/256, NEXP), 512, 0, stream>>>(
      hid_bf, gupT, (size_t)(2*INNER)*DIM, tok_idx, nullptr, nullptr, act_r, nullptr);
  // gemm2 shared: out = act_s @ shoutT (plain store initializes d_out)
  gemm8_kernel<false,false,false,false,INNER><<<dim3(DIM/256, NTOK/256, 1), 512, 0, stream>>>(
      act_s, shoutT, 0, nullptr, nullptr, nullptr, nullptr, out);
  // gemm2 routed: atomicAdd(out, acc * gate/(sums+eps))
  gemm8_kernel<false,false,true,false,INNER><<<dim3(DIM/256, TPE/256, NEXP), 512, 0, stream>>>(
      act_r, dwnT, (size_t)DIM*INNER, tok_idx, gate_raw, token_sums, nullptr, out);
}